// Round 12
// baseline (23382.771 us; speedup 1.0000x reference)
//
#include <hip/hip_runtime.h>

typedef __bf16 bf16x8 __attribute__((ext_vector_type(8)));
typedef float f32x4 __attribute__((ext_vector_type(4)));
typedef unsigned short u16;
typedef unsigned int u32;
typedef u16 u16x8 __attribute__((ext_vector_type(8)));

#define MFMA16(a, b, c) __builtin_amdgcn_mfma_f32_16x16x32_bf16((a), (b), (c), 0, 0, 0)

// ---------------------------------------------------------------------------
// R11 structure (22.06ms) with HOT-POLL group barriers (DVFS probe/mitigation).
// Hypothesis: per-round cost (~17us vs ~4us static estimate) is clock
// throttling from idle-looking waves (s_sleep + barrier-sleep). The t-loop
// barrier now keeps ALL waves spinning with a dependent-MFMA burn between
// polls; idle half1 blocks burn for entire rounds -> every CU looks busy.
// Everything else (numerics, layout, staging, stores) identical to R11.
//
// Grid 256x256: bid<128 = half0, bid>=128 = half1; rt=(bid&127)>>4,
// cb=(bid&15)*4+wid. Per-group (rt) sync: flat 32-participant AGENT epoch
// counter, own LLC line, memset-zeroed, bounded polls.
//
// Per step (5 group barriers):
//  A: half0 s0=f(W0@[x|h]) -> slot1
//  B: half0 s1 (sig)       -> slot2, reg rs1
//  C: half0 s2(relu)->slot3+rs2, s4(ident) reg-only; half1 s3(relu)->slot4
//  D: half0 s5(tanh on s2)->slot5+rs5;          half1 s7(tanh on s3)->slot6
//  E: half0 s6(sig),s8(relu) reg; mean(rs*,s3,s7 vec-read) -> out, h->slot0
//
// counters (4096B memset 0): gbar sub c*64 (c<8), top 512; group rt counter
//   at 576+rt*16. ws u16: Wh[5242880] @ byte 4096, Wl[5242880], S[7][131072]:
//   slots 0=h 1=s0 2=s1 3=s2 4=s3 5=s5 6=s7 (hi[8192]++lo[8192] per rt).
// ---------------------------------------------------------------------------

__device__ __forceinline__ u16 f2bf(float f) {
  u32 u = __float_as_uint(f);
  u += 0x7FFFu + ((u >> 16) & 1u);
  return (u16)(u >> 16);
}
__device__ __forceinline__ float bf2f(u32 h) { return __uint_as_float(h << 16); }
__device__ __forceinline__ void splitbf(float f, u16 &hi, u16 &lo) {
  hi = f2bf(f);
  lo = f2bf(f - bf2f((u32)hi));
}

__device__ __forceinline__ void issue_ld128_sc(bf16x8 &d, const u16 *p) {
  asm volatile("global_load_dwordx4 %0, %1, off sc0 sc1" : "=v"(d) : "v"(p));
}
__device__ __forceinline__ void issue_ld128u_sc(u16x8 &d, const u16 *p) {
  asm volatile("global_load_dwordx4 %0, %1, off sc0 sc1" : "=v"(d) : "v"(p));
}
__device__ __forceinline__ void st128_sc(u16 *p, u16x8 v) {
  asm volatile("global_store_dwordx4 %0, %1, off sc0 sc1" :: "v"(p), "v"(v) : "memory");
}
__device__ __forceinline__ void st16_sc(u16 *p, u16 v) {
  u32 q = v;
  asm volatile("global_store_short %0, %1, off sc0 sc1" :: "v"(p), "v"(q) : "memory");
}
__device__ __forceinline__ void wait_vm() {
  asm volatile("s_waitcnt vmcnt(0)" ::: "memory");
  __builtin_amdgcn_sched_barrier(0);
}
__device__ __forceinline__ void wait_vm_n(int n) {
  switch (n) {
    case 0: asm volatile("s_waitcnt vmcnt(0)" ::: "memory"); break;
    case 1: asm volatile("s_waitcnt vmcnt(1)" ::: "memory"); break;
    case 2: asm volatile("s_waitcnt vmcnt(2)" ::: "memory"); break;
    case 3: asm volatile("s_waitcnt vmcnt(3)" ::: "memory"); break;
    case 4: asm volatile("s_waitcnt vmcnt(4)" ::: "memory"); break;
    case 5: asm volatile("s_waitcnt vmcnt(5)" ::: "memory"); break;
    case 6: asm volatile("s_waitcnt vmcnt(6)" ::: "memory"); break;
    default: asm volatile("s_waitcnt vmcnt(7)" ::: "memory"); break;
  }
  __builtin_amdgcn_sched_barrier(0);
}

__device__ __forceinline__ int mbase(int m) {          // u16 elems; m=0 -> W0 (K=1024)
  return m == 0 ? 0 : 1048576 + (m - 1) * 524288;
}
__device__ __forceinline__ int lineOf(int row15, int scol) {
  return (scol >> 5) * 64 + row15 + ((scol >> 3) & 3) * 16;
}
__device__ __forceinline__ int goff(int slot, int row, int scol) {  // hi; lo at +8192
  return slot * 131072 + (row >> 4) * 16384 + lineOf(row & 15, scol) * 8 + (scol & 7);
}

template <int A> __device__ __forceinline__ float actf(float x) {
  if (A == 0) { float e = __expf(2.f * x); return 1.f - 2.f / (e + 1.f); } // tanh
  if (A == 1) return 1.f / (1.f + __expf(-x));                            // sigmoid
  if (A == 2) return fmaxf(x, 0.f);                                       // relu
  return x;                                                               // identity
}

__device__ __forceinline__ float lds_elem(const u16 *lds, int row15, int scol) {
  int o = lineOf(row15, scol) * 8 + (scol & 7);
  return bf2f(lds[o]) + bf2f(lds[o + 8192]);
}

// staged copy, counted-vmcnt ladder (entered with vmcnt==0 only)
__device__ __forceinline__ void stage_panel_cw(const u16 *S, int slot, int rt, u16 *lds, int tid) {
  const u16 *src = S + slot * 131072 + rt * 16384 + tid * 8;
  bf16x8 r[8];
#pragma unroll
  for (int i = 0; i < 8; ++i) issue_ld128_sc(r[i], src + i * 2048);
#pragma unroll
  for (int i = 0; i < 8; ++i) {
    wait_vm_n(7 - i);
    *(bf16x8 *)(lds + tid * 8 + i * 2048) = r[i];
  }
}
// full-drain variant (safe with concurrent outstanding VMEM, e.g. E prefetch)
__device__ __forceinline__ void stage_panel_drain(const u16 *S, int slot, int rt, u16 *lds, int tid) {
  const u16 *src = S + slot * 131072 + rt * 16384 + tid * 8;
  bf16x8 r[8];
#pragma unroll
  for (int i = 0; i < 8; ++i) issue_ld128_sc(r[i], src + i * 2048);
  wait_vm();
#pragma unroll
  for (int i = 0; i < 8; ++i) *(bf16x8 *)(lds + tid * 8 + i * 2048) = r[i];
}

template <int ACT>
__device__ __forceinline__ void act_only(f32x4 acc, const float *spv, float *sv) {
#pragma unroll
  for (int j = 0; j < 4; ++j) {
    float cp = acc[j];
    float hp = __shfl_xor(cp, 1);
    float sig = 1.f / (1.f + __expf(-cp));
    sv[j] = spv[j] + sig * (actf<ACT>(hp) - spv[j]);
  }
}

// vectorized state store: frag-layout sv -> per-wave LDS transpose -> 2x16B/row
__device__ __forceinline__ void store_state(const float *sv, u16 *S, int dslot,
                                            int rt, int cb, float *fscrw,
                                            int ln, int l4, int l15) {
  if ((l15 & 1) == 0) {
#pragma unroll
    for (int j = 0; j < 4; ++j) fscrw[(l4 * 4 + j) * 8 + (l15 >> 1)] = sv[j];
  }
  if (ln < 16) {
    u16x8 H, L;
#pragma unroll
    for (int c = 0; c < 8; ++c) {
      u16 hi, lo;
      splitbf(fscrw[ln * 8 + c], hi, lo);
      H[c] = hi; L[c] = lo;
    }
    u16 *p = S + goff(dslot, rt * 16 + ln, cb * 8);
    st128_sc(p, H);
    st128_sc(p + 8192, L);
  }
}

// K=512 GEMM; A-panel + s_prev from LDS; weights plain cached loads; no store
template <int ACT0, int ACT1, bool TWO>
__device__ __forceinline__ void gemm512(const u16 *Wh, const u16 *Wl, const u16 *lds,
                                        int m0, int m1, int cb, int ln, int l4, int l15,
                                        float *sv0, float *sv1) {
  float spv[4];
#pragma unroll
  for (int j = 0; j < 4; ++j) spv[j] = lds_elem(lds, l4 * 4 + j, cb * 8 + (l15 >> 1));
  f32x4 acc0 = {0.f, 0.f, 0.f, 0.f}, acc1 = {0.f, 0.f, 0.f, 0.f};
  const u16 *w0h = Wh + mbase(m0) + (cb * 16 * 64 + ln) * 8;
  const u16 *w0l = Wl + mbase(m0) + (cb * 16 * 64 + ln) * 8;
  const u16 *w1h = Wh + mbase(m1) + (cb * 16 * 64 + ln) * 8;
  const u16 *w1l = Wl + mbase(m1) + (cb * 16 * 64 + ln) * 8;
#pragma unroll
  for (int kc = 0; kc < 16; ++kc) {
    bf16x8 Ah = *(const bf16x8 *)(lds + (kc * 64 + ln) * 8);
    bf16x8 Al = *(const bf16x8 *)(lds + 8192 + (kc * 64 + ln) * 8);
    bf16x8 b0h = *(const bf16x8 *)(w0h + kc * 512);
    bf16x8 b0l = *(const bf16x8 *)(w0l + kc * 512);
    acc0 = MFMA16(Ah, b0h, acc0);
    acc0 = MFMA16(Ah, b0l, acc0);
    acc0 = MFMA16(Al, b0h, acc0);
    if (TWO) {
      bf16x8 b1h = *(const bf16x8 *)(w1h + kc * 512);
      bf16x8 b1l = *(const bf16x8 *)(w1l + kc * 512);
      acc1 = MFMA16(Ah, b1h, acc1);
      acc1 = MFMA16(Ah, b1l, acc1);
      acc1 = MFMA16(Al, b1h, acc1);
    }
  }
  float spv2[4];
#pragma unroll
  for (int j = 0; j < 4; ++j) spv2[j] = spv[j];
  act_only<ACT0>(acc0, spv, sv0);
  if (TWO) act_only<ACT1>(acc1, spv2, sv1);
}

// round A: s0 = h + sigmoid(c)*(tanh(h') - h); A = [x_t | h], K=1024, W0.
__device__ __forceinline__ void roundA(const float *xin, int t, const u16 *Wh, const u16 *Wl,
                                       const u16 *lds, int rt, int cb, int ln, int l4, int l15,
                                       float *sv) {
  float spv[4];
#pragma unroll
  for (int j = 0; j < 4; ++j) spv[j] = lds_elem(lds, l4 * 4 + j, cb * 8 + (l15 >> 1));
  f32x4 acc = {0.f, 0.f, 0.f, 0.f};
  const u16 *wh = Wh + (cb * 32 * 64 + ln) * 8;
  const u16 *wl = Wl + (cb * 32 * 64 + ln) * 8;
  const float *xp = xin + (t * 128 + rt * 16 + l15) * 512 + l4 * 8;
#pragma unroll
  for (int kc = 0; kc < 16; ++kc) {  // x half (k<512), on-the-fly hi/lo split
    f32x4 xa = *(const f32x4 *)(xp + kc * 32);
    f32x4 xb = *(const f32x4 *)(xp + kc * 32 + 4);
    union { u16 u[8]; bf16x8 v; } H, Lo;
#pragma unroll
    for (int e = 0; e < 4; ++e) {
      splitbf(xa[e], H.u[e], Lo.u[e]);
      splitbf(xb[e], H.u[4 + e], Lo.u[4 + e]);
    }
    bf16x8 bh = *(const bf16x8 *)(wh + kc * 512);
    bf16x8 bl = *(const bf16x8 *)(wl + kc * 512);
    acc = MFMA16(H.v, bh, acc);
    acc = MFMA16(H.v, bl, acc);
    acc = MFMA16(Lo.v, bh, acc);
  }
#pragma unroll
  for (int kc = 0; kc < 16; ++kc) {  // h half (k>=512), from staged LDS
    bf16x8 Ah = *(const bf16x8 *)(lds + (kc * 64 + ln) * 8);
    bf16x8 Al = *(const bf16x8 *)(lds + 8192 + (kc * 64 + ln) * 8);
    bf16x8 bh = *(const bf16x8 *)(wh + (16 + kc) * 512);
    bf16x8 bl = *(const bf16x8 *)(wl + (16 + kc) * 512);
    acc = MFMA16(Ah, bh, acc);
    acc = MFMA16(Ah, bl, acc);
    acc = MFMA16(Al, bh, acc);
  }
  act_only<0>(acc, spv, sv);
}

// global hierarchical epoch barrier (prologue only), bounded polls
__device__ __forceinline__ void gbar(u32 *cnt, u32 &ep, u32 &pb) {
  wait_vm();
  __syncthreads();
  ep += 256u;
  if (threadIdx.x == 0) {
    const int c = blockIdx.x & 7;
    u32 old = __hip_atomic_fetch_add(&cnt[c * 64], 1u, __ATOMIC_RELAXED, __HIP_MEMORY_SCOPE_AGENT);
    if (((old + 1u) & 31u) == 0u)
      __hip_atomic_fetch_add(&cnt[512], 32u, __ATOMIC_RELAXED, __HIP_MEMORY_SCOPE_AGENT);
    bool ok = false;
    for (u32 i = 0; i < pb; ++i) {
      u32 v = __hip_atomic_load(&cnt[512], __ATOMIC_RELAXED, __HIP_MEMORY_SCOPE_AGENT);
      if ((int)(v - ep) >= 0) { ok = true; break; }
      __builtin_amdgcn_s_sleep(2);
    }
    if (!ok) pb = 4096u;
  }
  __syncthreads();
}

// HOT per-group barrier: 32 participants, one LLC line. ALL waves poll with a
// dependent-MFMA burn between polls — no s_sleep, no idle-looking waves.
// DVFS probe/mitigation: keeps every CU's matrix pipe active while waiting.
__device__ __forceinline__ void grbar_hot(u32 *gc, u32 &gep, u32 &pb, int tid) {
  wait_vm();   // drain this wave's sc-stores to LLC before arrival
  __syncthreads();
  gep += 32u;
  if (tid == 0)
    __hip_atomic_fetch_add(gc, 1u, __ATOMIC_RELAXED, __HIP_MEMORY_SCOPE_AGENT);
  // hot poll in every wave (same addr across lanes -> one transaction/wave)
  union { u32 u[8]; bf16x8 v; } j8;
#pragma unroll
  for (int i = 0; i < 8; ++i) j8.u[i] = 0x3f803f80u;  // bf16 1.0 pairs
  f32x4 bacc = {0.f, 0.f, 0.f, 0.f};
  bool ok = false;
  for (u32 i = 0; i < pb; ++i) {
    u32 v = __hip_atomic_load(gc, __ATOMIC_RELAXED, __HIP_MEMORY_SCOPE_AGENT);
    if ((int)(v - gep) >= 0) { ok = true; break; }
#pragma unroll
    for (int b = 0; b < 8; ++b) bacc = MFMA16(j8.v, j8.v, bacc);  // ~200cyc burn
  }
  asm volatile("" :: "v"(bacc));  // keep burn live (no DCE)
  if (!ok) pb = 4096u;
  __syncthreads();
}

__global__ __launch_bounds__(256, 1) void darts_rnn(
    const float *__restrict__ xin, const float *__restrict__ h0in,
    const float *__restrict__ W0, const float *__restrict__ Wsi,
    float *__restrict__ out, u16 *__restrict__ wsu) {
  __shared__ u16 smem[16384];      // 32KB staging panel
  __shared__ float fscr[4][128];   // per-wave transpose scratch
  u32 *cnt = (u32 *)wsu;
  u16 *Wh = wsu + 2048;            // byte 4096
  u16 *Wl = Wh + 5242880;
  u16 *S = Wl + 5242880;

  const int tid = threadIdx.x, bid = blockIdx.x;
  const int ln = tid & 63, wid = tid >> 6;
  const int l15 = ln & 15, l4 = ln >> 4;
  const int rt = (bid & 127) >> 4;
  const int cb = (bid & 15) * 4 + wid;
  float *fscrw = fscr[wid];
  u32 *gc = cnt + 576 + rt * 16;   // group counter, own 64B line

  u32 ep = 0, pb = 1u << 22;

  // ---- hygiene: flush dirty ws lines (poison), then invalidate L2 ----
  if (wid == 0) asm volatile("buffer_wbl2 sc1" ::: "memory");
  wait_vm();
  gbar(cnt, ep, pb);
  if (wid == 0) asm volatile("buffer_inv sc1" ::: "memory");
  wait_vm();
  gbar(cnt, ep, pb);

  // ---- P0: weight hi/lo split into fragment layout ----
  for (int idx = bid * 256 + tid; idx < 5242880; idx += 65536) {
    int mk = idx >> 10, oc = idx & 1023;
    int m, k;
    if (mk < 1024) { m = 0; k = mk; } else { m = 1 + ((mk - 1024) >> 9); k = (mk - 1024) & 511; }
    float v = (m == 0) ? W0[k * 1024 + oc] : Wsi[((m - 1) * 512 + k) * 1024 + oc];
    int colp = (oc < 512) ? (oc * 2) : ((oc - 512) * 2 + 1);  // interleave c,h cols
    int cbw = colp >> 4;
    int kc = k >> 5;
    int lnn = (colp & 15) + ((k >> 3) & 3) * 16;
    int el = k & 7;
    int lineBase = (m == 0) ? (cbw * 32 + kc) : (cbw * 16 + kc);  // W0: K=1024
    int e = mbase(m) + (lineBase * 64 + lnn) * 8 + el;
    u16 hi, lo; splitbf(v, hi, lo);
    st16_sc(Wh + e, hi);
    st16_sc(Wl + e, lo);
  }
  {  // h0 -> slot 0
    int g = bid * 256 + tid;         // 65536 = 128*512
    int row = g >> 9, k = g & 511;
    u16 hi, lo; splitbf(h0in[g], hi, lo);
    int o = goff(0, row, k);
    st16_sc(S + o, hi);
    st16_sc(S + o + 8192, lo);
  }
  gbar(cnt, ep, pb);

  u32 gep = 0;
  for (int t = 0; t < 256; ++t) {
    float rs1[4], rs2[4], rs4[4], rs5[4], dum[4];
    // ---- round A: half0: s0 <- W0 @ [x_t | h] -> slot1 ----
    if (bid < 128) {
      stage_panel_cw(S, 0, rt, smem, tid);
      __syncthreads();
      float sv[4];
      roundA(xin, t, Wh, Wl, smem, rt, cb, ln, l4, l15, sv);
      store_state(sv, S, 1, rt, cb, fscrw, ln, l4, l15);
    }
    grbar_hot(gc, gep, pb, tid);
    // ---- round B: half0: s1 <- Ws0(sig) on s0 -> slot2, reg rs1 ----
    if (bid < 128) {
      stage_panel_cw(S, 1, rt, smem, tid);
      __syncthreads();
      gemm512<1, 1, false>(Wh, Wl, smem, 1, 1, cb, ln, l4, l15, rs1, dum);
      store_state(rs1, S, 2, rt, cb, fscrw, ln, l4, l15);
    }
    grbar_hot(gc, gep, pb, tid);
    // ---- round C: A = s1. half0: s2(relu)->slot3+rs2, s4(ident) reg;
    //                        half1: s3(relu)->slot4 ----
    stage_panel_cw(S, 2, rt, smem, tid);
    __syncthreads();
    if (bid < 128) {
      gemm512<2, 3, true>(Wh, Wl, smem, 2, 4, cb, ln, l4, l15, rs2, rs4);
      store_state(rs2, S, 3, rt, cb, fscrw, ln, l4, l15);
    } else {
      float sv[4];
      gemm512<2, 2, false>(Wh, Wl, smem, 3, 3, cb, ln, l4, l15, sv, dum);
      store_state(sv, S, 4, rt, cb, fscrw, ln, l4, l15);
    }
    grbar_hot(gc, gep, pb, tid);
    // ---- round D: half0: s5(tanh) on s2 -> slot5+rs5; half1: s7 on s3 -> slot6 ----
    stage_panel_cw(S, (bid < 128) ? 3 : 4, rt, smem, tid);
    __syncthreads();
    if (bid < 128) {
      gemm512<0, 0, false>(Wh, Wl, smem, 5, 5, cb, ln, l4, l15, rs5, dum);
      store_state(rs5, S, 5, rt, cb, fscrw, ln, l4, l15);
    } else {
      float sv[4];
      gemm512<0, 0, false>(Wh, Wl, smem, 7, 7, cb, ln, l4, l15, sv, dum);
      store_state(sv, S, 6, rt, cb, fscrw, ln, l4, l15);
    }
    grbar_hot(gc, gep, pb, tid);
    // ---- round E: half0: s6(sig),s8(relu) on s5; mean -> out, h -> slot0 ----
    if (bid < 128) {
      u16x8 p3h, p3l, p7h, p7l;
      if (ln < 16) {  // prefetch s3,s7 row-slices; latency hides under stage+gemm
        const u16 *p3 = S + goff(4, rt * 16 + ln, cb * 8);
        const u16 *p7 = S + goff(6, rt * 16 + ln, cb * 8);
        issue_ld128u_sc(p3h, p3);
        issue_ld128u_sc(p3l, p3 + 8192);
        issue_ld128u_sc(p7h, p7);
        issue_ld128u_sc(p7l, p7 + 8192);
      }
      stage_panel_drain(S, 5, rt, smem, tid);   // full drain covers prefetch
      __syncthreads();
      float sv6[4], sv8[4];
      gemm512<1, 2, true>(Wh, Wl, smem, 6, 8, cb, ln, l4, l15, sv6, sv8);
      if ((l15 & 1) == 0) {
#pragma unroll
        for (int j = 0; j < 4; ++j)
          fscrw[(l4 * 4 + j) * 8 + (l15 >> 1)] = rs1[j] + rs2[j] + rs4[j] + rs5[j] + sv6[j] + sv8[j];
      }
      if (ln < 16) {
        float o0[8];
        u16x8 H, L;
#pragma unroll
        for (int c = 0; c < 8; ++c) {
          float v = fscrw[ln * 8 + c];
          v += bf2f(p3h[c]) + bf2f(p3l[c]);
          v += bf2f(p7h[c]) + bf2f(p7l[c]);
          float hnew = v * 0.125f;
          o0[c] = hnew;
          u16 hi, lo; splitbf(hnew, hi, lo);
          H[c] = hi; L[c] = lo;
        }
        int row = rt * 16 + ln;
        float *op = out + t * 65536 + row * 512 + cb * 8;
        *(f32x4 *)op = *(f32x4 *)&o0[0];
        *(f32x4 *)(op + 4) = *(f32x4 *)&o0[4];
        if (t == 255) {
          float *op2 = out + 16777216 + row * 512 + cb * 8;
          *(f32x4 *)op2 = *(f32x4 *)&o0[0];
          *(f32x4 *)(op2 + 4) = *(f32x4 *)&o0[4];
        }
        u16 *p = S + goff(0, row, cb * 8);
        st128_sc(p, H);
        st128_sc(p + 8192, L);
      }
    }
    grbar_hot(gc, gep, pb, tid);
  }
}

extern "C" void kernel_launch(void *const *d_in, const int *in_sizes, int n_in,
                              void *d_out, int out_size, void *d_ws, size_t ws_size,
                              hipStream_t stream) {
  const float *x = (const float *)d_in[0];
  const float *h0 = (const float *)d_in[1];
  const float *W0 = (const float *)d_in[2];
  const float *Ws = (const float *)d_in[3];
  float *out = (float *)d_out;
  u16 *ws = (u16 *)d_ws;

  hipMemsetAsync(d_ws, 0, 4096, stream);  // zero barrier counters

  void *args[] = {(void *)&x, (void *)&h0, (void *)&W0, (void *)&Ws, (void *)&out, (void *)&ws};
  hipError_t err = hipLaunchCooperativeKernel((void *)darts_rnn, dim3(256), dim3(256),
                                              args, 0, stream);
  if (err != hipSuccess) {
    (void)hipGetLastError();
    darts_rnn<<<dim3(256), dim3(256), 0, stream>>>(x, h0, W0, Ws, out, ws);
  }
}

// Round 13
// 18906.795 us; speedup vs baseline: 1.2367x; 1.2367x over previous
//
#include <hip/hip_runtime.h>

typedef __bf16 bf16x8 __attribute__((ext_vector_type(8)));
typedef float f32x4 __attribute__((ext_vector_type(4)));
typedef unsigned short u16;
typedef unsigned int u32;
typedef u16 u16x8 __attribute__((ext_vector_type(8)));

#define MFMA16(a, b, c) __builtin_amdgcn_mfma_f32_16x16x32_bf16((a), (b), (c), 0, 0, 0)

// ---------------------------------------------------------------------------
// R11 data path (22.06ms) with POINT-TO-POINT EPOCH TAGS instead of barriers.
// Producers: data stores (sc0sc1) -> wait_vm -> __syncthreads -> tid0 stores
// tag[slot][rt][p]=t+1 (AGENT/LLC). Consumers: poll the 64B tag line (16
// lanes, one load/iter) for >= need, then stage. Each hop = ~3 LLC RTTs
// (drain, poll, load) vs ~5 for the barrier scheme. No collective sync in the
// t-loop; groups and half-chains drift freely.
//
// WAR safety WITHOUT double-buffering (verified per slot): every slot's next
// write is gated through a tag chain that transitively passes through every
// reader's staging of the previous value. E.g. slot1 rewritten at A[t+1]
// <- slot0>=t+1 <- all E[t] <- slot5/4/6 <- ... <- every block staged
// slot1[t] at B[t] before publishing slot2[t].
//
// Per step: half0: A(slot0->slot1) B(->slot2) C(->slot3, s4 reg) D(->slot5)
//           E(slot5 + slot4,slot6 reads -> out, slot0).  half1: C'(slot2->
//           slot4) D'(slot4->slot6). s4/s6/s8 never touch memory (reg-carry).
//
// counters (32768B memset 0): prologue gbar sub c*64 (c<8), top 512;
//   tags u32 at 1024 + (slot*8+rt)*16 + p  (7 slots x 8 rt x 16 producers).
// ws u16: Wh[5242880] @ byte 32768, Wl[5242880], S[7][131072]: slots
//   0=h 1=s0 2=s1 3=s2 4=s3 5=s5 6=s7 (per (slot,rt): hi[8192]++lo[8192]).
// All polls bounded; first timeout collapses budget -> finish-wrong, no hang.
// ---------------------------------------------------------------------------

__device__ __forceinline__ u16 f2bf(float f) {
  u32 u = __float_as_uint(f);
  u += 0x7FFFu + ((u >> 16) & 1u);
  return (u16)(u >> 16);
}
__device__ __forceinline__ float bf2f(u32 h) { return __uint_as_float(h << 16); }
__device__ __forceinline__ void splitbf(float f, u16 &hi, u16 &lo) {
  hi = f2bf(f);
  lo = f2bf(f - bf2f((u32)hi));
}

__device__ __forceinline__ void issue_ld128_sc(bf16x8 &d, const u16 *p) {
  asm volatile("global_load_dwordx4 %0, %1, off sc0 sc1" : "=v"(d) : "v"(p));
}
__device__ __forceinline__ void issue_ld128u_sc(u16x8 &d, const u16 *p) {
  asm volatile("global_load_dwordx4 %0, %1, off sc0 sc1" : "=v"(d) : "v"(p));
}
__device__ __forceinline__ void st128_sc(u16 *p, u16x8 v) {
  asm volatile("global_store_dwordx4 %0, %1, off sc0 sc1" :: "v"(p), "v"(v) : "memory");
}
__device__ __forceinline__ void st16_sc(u16 *p, u16 v) {
  u32 q = v;
  asm volatile("global_store_short %0, %1, off sc0 sc1" :: "v"(p), "v"(q) : "memory");
}
__device__ __forceinline__ void wait_vm() {
  asm volatile("s_waitcnt vmcnt(0)" ::: "memory");
  __builtin_amdgcn_sched_barrier(0);
}
__device__ __forceinline__ void wait_vm_n(int n) {
  switch (n) {
    case 0: asm volatile("s_waitcnt vmcnt(0)" ::: "memory"); break;
    case 1: asm volatile("s_waitcnt vmcnt(1)" ::: "memory"); break;
    case 2: asm volatile("s_waitcnt vmcnt(2)" ::: "memory"); break;
    case 3: asm volatile("s_waitcnt vmcnt(3)" ::: "memory"); break;
    case 4: asm volatile("s_waitcnt vmcnt(4)" ::: "memory"); break;
    case 5: asm volatile("s_waitcnt vmcnt(5)" ::: "memory"); break;
    case 6: asm volatile("s_waitcnt vmcnt(6)" ::: "memory"); break;
    default: asm volatile("s_waitcnt vmcnt(7)" ::: "memory"); break;
  }
  __builtin_amdgcn_sched_barrier(0);
}

__device__ __forceinline__ int mbase(int m) {          // u16 elems; m=0 -> W0 (K=1024)
  return m == 0 ? 0 : 1048576 + (m - 1) * 524288;
}
__device__ __forceinline__ int lineOf(int row15, int scol) {
  return (scol >> 5) * 64 + row15 + ((scol >> 3) & 3) * 16;
}
__device__ __forceinline__ int goff(int slot, int row, int scol) {  // hi; lo at +8192
  return slot * 131072 + (row >> 4) * 16384 + lineOf(row & 15, scol) * 8 + (scol & 7);
}

template <int A> __device__ __forceinline__ float actf(float x) {
  if (A == 0) { float e = __expf(2.f * x); return 1.f - 2.f / (e + 1.f); } // tanh
  if (A == 1) return 1.f / (1.f + __expf(-x));                            // sigmoid
  if (A == 2) return fmaxf(x, 0.f);                                       // relu
  return x;                                                               // identity
}

__device__ __forceinline__ float lds_elem(const u16 *lds, int row15, int scol) {
  int o = lineOf(row15, scol) * 8 + (scol & 7);
  return bf2f(lds[o]) + bf2f(lds[o + 8192]);
}

// staged copy, counted-vmcnt ladder (entered with vmcnt==0 only)
__device__ __forceinline__ void stage_panel_cw(const u16 *S, int slot, int rt, u16 *lds, int tid) {
  const u16 *src = S + slot * 131072 + rt * 16384 + tid * 8;
  bf16x8 r[8];
#pragma unroll
  for (int i = 0; i < 8; ++i) issue_ld128_sc(r[i], src + i * 2048);
#pragma unroll
  for (int i = 0; i < 8; ++i) {
    wait_vm_n(7 - i);
    *(bf16x8 *)(lds + tid * 8 + i * 2048) = r[i];
  }
}
// full-drain variant (safe with concurrent outstanding VMEM, e.g. E prefetch)
__device__ __forceinline__ void stage_panel_drain(const u16 *S, int slot, int rt, u16 *lds, int tid) {
  const u16 *src = S + slot * 131072 + rt * 16384 + tid * 8;
  bf16x8 r[8];
#pragma unroll
  for (int i = 0; i < 8; ++i) issue_ld128_sc(r[i], src + i * 2048);
  wait_vm();
#pragma unroll
  for (int i = 0; i < 8; ++i) *(bf16x8 *)(lds + tid * 8 + i * 2048) = r[i];
}

template <int ACT>
__device__ __forceinline__ void act_only(f32x4 acc, const float *spv, float *sv) {
#pragma unroll
  for (int j = 0; j < 4; ++j) {
    float cp = acc[j];
    float hp = __shfl_xor(cp, 1);
    float sig = 1.f / (1.f + __expf(-cp));
    sv[j] = spv[j] + sig * (actf<ACT>(hp) - spv[j]);
  }
}

// vectorized state store: frag-layout sv -> per-wave LDS transpose -> 2x16B/row
__device__ __forceinline__ void store_state(const float *sv, u16 *S, int dslot,
                                            int rt, int cb, float *fscrw,
                                            int ln, int l4, int l15) {
  if ((l15 & 1) == 0) {
#pragma unroll
    for (int j = 0; j < 4; ++j) fscrw[(l4 * 4 + j) * 8 + (l15 >> 1)] = sv[j];
  }
  if (ln < 16) {
    u16x8 H, L;
#pragma unroll
    for (int c = 0; c < 8; ++c) {
      u16 hi, lo;
      splitbf(fscrw[ln * 8 + c], hi, lo);
      H[c] = hi; L[c] = lo;
    }
    u16 *p = S + goff(dslot, rt * 16 + ln, cb * 8);
    st128_sc(p, H);
    st128_sc(p + 8192, L);
  }
}

// K=512 GEMM; A-panel + s_prev from LDS; weights plain cached loads; no store
template <int ACT0, int ACT1, bool TWO>
__device__ __forceinline__ void gemm512(const u16 *Wh, const u16 *Wl, const u16 *lds,
                                        int m0, int m1, int cb, int ln, int l4, int l15,
                                        float *sv0, float *sv1) {
  float spv[4];
#pragma unroll
  for (int j = 0; j < 4; ++j) spv[j] = lds_elem(lds, l4 * 4 + j, cb * 8 + (l15 >> 1));
  f32x4 acc0 = {0.f, 0.f, 0.f, 0.f}, acc1 = {0.f, 0.f, 0.f, 0.f};
  const u16 *w0h = Wh + mbase(m0) + (cb * 16 * 64 + ln) * 8;
  const u16 *w0l = Wl + mbase(m0) + (cb * 16 * 64 + ln) * 8;
  const u16 *w1h = Wh + mbase(m1) + (cb * 16 * 64 + ln) * 8;
  const u16 *w1l = Wl + mbase(m1) + (cb * 16 * 64 + ln) * 8;
#pragma unroll
  for (int kc = 0; kc < 16; ++kc) {
    bf16x8 Ah = *(const bf16x8 *)(lds + (kc * 64 + ln) * 8);
    bf16x8 Al = *(const bf16x8 *)(lds + 8192 + (kc * 64 + ln) * 8);
    bf16x8 b0h = *(const bf16x8 *)(w0h + kc * 512);
    bf16x8 b0l = *(const bf16x8 *)(w0l + kc * 512);
    acc0 = MFMA16(Ah, b0h, acc0);
    acc0 = MFMA16(Ah, b0l, acc0);
    acc0 = MFMA16(Al, b0h, acc0);
    if (TWO) {
      bf16x8 b1h = *(const bf16x8 *)(w1h + kc * 512);
      bf16x8 b1l = *(const bf16x8 *)(w1l + kc * 512);
      acc1 = MFMA16(Ah, b1h, acc1);
      acc1 = MFMA16(Ah, b1l, acc1);
      acc1 = MFMA16(Al, b1h, acc1);
    }
  }
  float spv2[4];
#pragma unroll
  for (int j = 0; j < 4; ++j) spv2[j] = spv[j];
  act_only<ACT0>(acc0, spv, sv0);
  if (TWO) act_only<ACT1>(acc1, spv2, sv1);
}

// round A: s0 = h + sigmoid(c)*(tanh(h') - h); A = [x_t | h], K=1024, W0.
__device__ __forceinline__ void roundA(const float *xin, int t, const u16 *Wh, const u16 *Wl,
                                       const u16 *lds, int rt, int cb, int ln, int l4, int l15,
                                       float *sv) {
  float spv[4];
#pragma unroll
  for (int j = 0; j < 4; ++j) spv[j] = lds_elem(lds, l4 * 4 + j, cb * 8 + (l15 >> 1));
  f32x4 acc = {0.f, 0.f, 0.f, 0.f};
  const u16 *wh = Wh + (cb * 32 * 64 + ln) * 8;
  const u16 *wl = Wl + (cb * 32 * 64 + ln) * 8;
  const float *xp = xin + (t * 128 + rt * 16 + l15) * 512 + l4 * 8;
#pragma unroll
  for (int kc = 0; kc < 16; ++kc) {  // x half (k<512), on-the-fly hi/lo split
    f32x4 xa = *(const f32x4 *)(xp + kc * 32);
    f32x4 xb = *(const f32x4 *)(xp + kc * 32 + 4);
    union { u16 u[8]; bf16x8 v; } H, Lo;
#pragma unroll
    for (int e = 0; e < 4; ++e) {
      splitbf(xa[e], H.u[e], Lo.u[e]);
      splitbf(xb[e], H.u[4 + e], Lo.u[4 + e]);
    }
    bf16x8 bh = *(const bf16x8 *)(wh + kc * 512);
    bf16x8 bl = *(const bf16x8 *)(wl + kc * 512);
    acc = MFMA16(H.v, bh, acc);
    acc = MFMA16(H.v, bl, acc);
    acc = MFMA16(Lo.v, bh, acc);
  }
#pragma unroll
  for (int kc = 0; kc < 16; ++kc) {  // h half (k>=512), from staged LDS
    bf16x8 Ah = *(const bf16x8 *)(lds + (kc * 64 + ln) * 8);
    bf16x8 Al = *(const bf16x8 *)(lds + 8192 + (kc * 64 + ln) * 8);
    bf16x8 bh = *(const bf16x8 *)(wh + (16 + kc) * 512);
    bf16x8 bl = *(const bf16x8 *)(wl + (16 + kc) * 512);
    acc = MFMA16(Ah, bh, acc);
    acc = MFMA16(Ah, bl, acc);
    acc = MFMA16(Al, bh, acc);
  }
  act_only<0>(acc, spv, sv);
}

// global hierarchical epoch barrier (prologue only), bounded polls
__device__ __forceinline__ void gbar(u32 *cnt, u32 &ep, u32 &pb) {
  wait_vm();
  __syncthreads();
  ep += 256u;
  if (threadIdx.x == 0) {
    const int c = blockIdx.x & 7;
    u32 old = __hip_atomic_fetch_add(&cnt[c * 64], 1u, __ATOMIC_RELAXED, __HIP_MEMORY_SCOPE_AGENT);
    if (((old + 1u) & 31u) == 0u)
      __hip_atomic_fetch_add(&cnt[512], 32u, __ATOMIC_RELAXED, __HIP_MEMORY_SCOPE_AGENT);
    bool ok = false;
    for (u32 i = 0; i < pb; ++i) {
      u32 v = __hip_atomic_load(&cnt[512], __ATOMIC_RELAXED, __HIP_MEMORY_SCOPE_AGENT);
      if ((int)(v - ep) >= 0) { ok = true; break; }
      __builtin_amdgcn_s_sleep(2);
    }
    if (!ok) pb = 4096u;
  }
  __syncthreads();
}

// wait until all 16 tags of one line are >= need (wave0 polls, 1 line-load/iter)
__device__ __forceinline__ void wait_tags(const u32 *line, u32 need, u32 &pb, int tid) {
  if (tid < 64) {
    const u32 *p = line + (tid & 15);
    const bool mine = tid < 16;
    bool ok = false;
    for (u32 i = 0; i < pb; ++i) {
      u32 v = mine ? __hip_atomic_load(p, __ATOMIC_RELAXED, __HIP_MEMORY_SCOPE_AGENT) : need;
      if (__all((int)(v - need) >= 0)) { ok = true; break; }
    }
    if (!ok) pb = 4096u;
  }
  __syncthreads();
}
// wait on three tag lines at once (lanes 0-15,16-31,32-47)
__device__ __forceinline__ void wait_tags3(const u32 *a, const u32 *b, const u32 *c,
                                           u32 need, u32 &pb, int tid) {
  if (tid < 64) {
    const u32 *p = (tid < 16) ? a + tid : (tid < 32) ? b + (tid - 16)
                  : (tid < 48) ? c + (tid - 32) : a;
    const bool mine = tid < 48;
    bool ok = false;
    for (u32 i = 0; i < pb; ++i) {
      u32 v = mine ? __hip_atomic_load(p, __ATOMIC_RELAXED, __HIP_MEMORY_SCOPE_AGENT) : need;
      if (__all((int)(v - need) >= 0)) { ok = true; break; }
    }
    if (!ok) pb = 4096u;
  }
  __syncthreads();
}

__global__ __launch_bounds__(256, 1) void darts_rnn(
    const float *__restrict__ xin, const float *__restrict__ h0in,
    const float *__restrict__ W0, const float *__restrict__ Wsi,
    float *__restrict__ out, u16 *__restrict__ wsu) {
  __shared__ u16 smem[16384];      // 32KB staging panel
  __shared__ float fscr[4][128];   // per-wave transpose scratch
  u32 *cnt = (u32 *)wsu;
  u16 *Wh = wsu + 16384;           // byte 32768
  u16 *Wl = Wh + 5242880;
  u16 *S = Wl + 5242880;

  const int tid = threadIdx.x, bid = blockIdx.x;
  const int ln = tid & 63, wid = tid >> 6;
  const int l15 = ln & 15, l4 = ln >> 4;
  const int rt = (bid & 127) >> 4;
  const int cb = (bid & 15) * 4 + wid;
  const int pidx = bid & 15;       // producer index within the 16-block set
  float *fscrw = fscr[wid];
  // tag line for (slot s, rt): cnt + 1024 + (s*8+rt)*16
#define TAGL(s) (cnt + 1024 + ((s) * 8 + rt) * 16)

  u32 ep = 0, pb = 1u << 21;

  // ---- hygiene: flush dirty ws lines (poison), then invalidate L2 ----
  if (wid == 0) asm volatile("buffer_wbl2 sc1" ::: "memory");
  wait_vm();
  gbar(cnt, ep, pb);
  if (wid == 0) asm volatile("buffer_inv sc1" ::: "memory");
  wait_vm();
  gbar(cnt, ep, pb);

  // ---- P0: weight hi/lo split into fragment layout ----
  for (int idx = bid * 256 + tid; idx < 5242880; idx += 65536) {
    int mk = idx >> 10, oc = idx & 1023;
    int m, k;
    if (mk < 1024) { m = 0; k = mk; } else { m = 1 + ((mk - 1024) >> 9); k = (mk - 1024) & 511; }
    float v = (m == 0) ? W0[k * 1024 + oc] : Wsi[((m - 1) * 512 + k) * 1024 + oc];
    int colp = (oc < 512) ? (oc * 2) : ((oc - 512) * 2 + 1);  // interleave c,h cols
    int cbw = colp >> 4;
    int kc = k >> 5;
    int lnn = (colp & 15) + ((k >> 3) & 3) * 16;
    int el = k & 7;
    int lineBase = (m == 0) ? (cbw * 32 + kc) : (cbw * 16 + kc);  // W0: K=1024
    int e = mbase(m) + (lineBase * 64 + lnn) * 8 + el;
    u16 hi, lo; splitbf(v, hi, lo);
    st16_sc(Wh + e, hi);
    st16_sc(Wl + e, lo);
  }
  {  // h0 -> slot 0
    int g = bid * 256 + tid;         // 65536 = 128*512
    int row = g >> 9, k = g & 511;
    u16 hi, lo; splitbf(h0in[g], hi, lo);
    int o = goff(0, row, k);
    st16_sc(S + o, hi);
    st16_sc(S + o + 8192, lo);
  }
  gbar(cnt, ep, pb);   // weights + h0 panels + zeroed tags visible everywhere

  if (bid < 128) {
    // ================= half0 chain: A B C D E per step =================
    for (int t = 0; t < 256; ++t) {
      const u32 tv = (u32)(t + 1);
      float rs1[4], rs2[4], rs4[4], rs5[4], dum[4];
      // ---- A: slot0 -> s0 -> slot1 ----
      wait_tags(TAGL(0), (u32)t, pb, tid);   // E[t-1] published t (t=0 trivial)
      stage_panel_cw(S, 0, rt, smem, tid);
      __syncthreads();
      {
        float sv[4];
        roundA(xin, t, Wh, Wl, smem, rt, cb, ln, l4, l15, sv);
        store_state(sv, S, 1, rt, cb, fscrw, ln, l4, l15);
      }
      wait_vm(); __syncthreads();
      if (tid == 0)
        __hip_atomic_store(TAGL(1) + pidx, tv, __ATOMIC_RELAXED, __HIP_MEMORY_SCOPE_AGENT);
      // ---- B: slot1 -> s1 (sig) -> slot2, reg rs1 ----
      wait_tags(TAGL(1), tv, pb, tid);
      stage_panel_cw(S, 1, rt, smem, tid);
      __syncthreads();
      gemm512<1, 1, false>(Wh, Wl, smem, 1, 1, cb, ln, l4, l15, rs1, dum);
      store_state(rs1, S, 2, rt, cb, fscrw, ln, l4, l15);
      wait_vm(); __syncthreads();
      if (tid == 0)
        __hip_atomic_store(TAGL(2) + pidx, tv, __ATOMIC_RELAXED, __HIP_MEMORY_SCOPE_AGENT);
      // ---- C: slot2 -> s2(relu)->slot3+rs2, s4(ident) reg-only ----
      wait_tags(TAGL(2), tv, pb, tid);
      stage_panel_cw(S, 2, rt, smem, tid);
      __syncthreads();
      gemm512<2, 3, true>(Wh, Wl, smem, 2, 4, cb, ln, l4, l15, rs2, rs4);
      store_state(rs2, S, 3, rt, cb, fscrw, ln, l4, l15);
      wait_vm(); __syncthreads();
      if (tid == 0)
        __hip_atomic_store(TAGL(3) + pidx, tv, __ATOMIC_RELAXED, __HIP_MEMORY_SCOPE_AGENT);
      // ---- D: slot3 -> s5(tanh) -> slot5 + rs5 ----
      wait_tags(TAGL(3), tv, pb, tid);
      stage_panel_cw(S, 3, rt, smem, tid);
      __syncthreads();
      gemm512<0, 0, false>(Wh, Wl, smem, 5, 5, cb, ln, l4, l15, rs5, dum);
      store_state(rs5, S, 5, rt, cb, fscrw, ln, l4, l15);
      wait_vm(); __syncthreads();
      if (tid == 0)
        __hip_atomic_store(TAGL(5) + pidx, tv, __ATOMIC_RELAXED, __HIP_MEMORY_SCOPE_AGENT);
      // ---- E: slot5 -> s6(sig),s8(relu) reg; mean(+slot4,slot6) -> out, slot0 ----
      wait_tags3(TAGL(5), TAGL(4), TAGL(6), tv, pb, tid);
      u16x8 p3h, p3l, p7h, p7l;
      if (ln < 16) {  // prefetch s3,s7 row-slices (tags confirmed above)
        const u16 *p3 = S + goff(4, rt * 16 + ln, cb * 8);
        const u16 *p7 = S + goff(6, rt * 16 + ln, cb * 8);
        issue_ld128u_sc(p3h, p3);
        issue_ld128u_sc(p3l, p3 + 8192);
        issue_ld128u_sc(p7h, p7);
        issue_ld128u_sc(p7l, p7 + 8192);
      }
      stage_panel_drain(S, 5, rt, smem, tid);   // full drain covers prefetch
      __syncthreads();
      {
        float sv6[4], sv8[4];
        gemm512<1, 2, true>(Wh, Wl, smem, 6, 8, cb, ln, l4, l15, sv6, sv8);
        if ((l15 & 1) == 0) {
#pragma unroll
          for (int j = 0; j < 4; ++j)
            fscrw[(l4 * 4 + j) * 8 + (l15 >> 1)] =
                rs1[j] + rs2[j] + rs4[j] + rs5[j] + sv6[j] + sv8[j];
        }
        if (ln < 16) {
          float o0[8];
          u16x8 H, L;
#pragma unroll
          for (int c = 0; c < 8; ++c) {
            float v = fscrw[ln * 8 + c];
            v += bf2f(p3h[c]) + bf2f(p3l[c]);
            v += bf2f(p7h[c]) + bf2f(p7l[c]);
            float hnew = v * 0.125f;
            o0[c] = hnew;
            u16 hi, lo; splitbf(hnew, hi, lo);
            H[c] = hi; L[c] = lo;
          }
          int row = rt * 16 + ln;
          float *op = out + t * 65536 + row * 512 + cb * 8;
          *(f32x4 *)op = *(f32x4 *)&o0[0];
          *(f32x4 *)(op + 4) = *(f32x4 *)&o0[4];
          if (t == 255) {
            float *op2 = out + 16777216 + row * 512 + cb * 8;
            *(f32x4 *)op2 = *(f32x4 *)&o0[0];
            *(f32x4 *)(op2 + 4) = *(f32x4 *)&o0[4];
          }
          u16 *p = S + goff(0, row, cb * 8);
          st128_sc(p, H);
          st128_sc(p + 8192, L);
        }
      }
      wait_vm(); __syncthreads();
      if (tid == 0)
        __hip_atomic_store(TAGL(0) + pidx, tv, __ATOMIC_RELAXED, __HIP_MEMORY_SCOPE_AGENT);
    }
  } else {
    // ================= half1 chain: C' D' per step =================
    for (int t = 0; t < 256; ++t) {
      const u32 tv = (u32)(t + 1);
      float dum[4];
      // ---- C': slot2 -> s3(relu) -> slot4 ----
      wait_tags(TAGL(2), tv, pb, tid);
      stage_panel_cw(S, 2, rt, smem, tid);
      __syncthreads();
      {
        float sv[4];
        gemm512<2, 2, false>(Wh, Wl, smem, 3, 3, cb, ln, l4, l15, sv, dum);
        store_state(sv, S, 4, rt, cb, fscrw, ln, l4, l15);
      }
      wait_vm(); __syncthreads();
      if (tid == 0)
        __hip_atomic_store(TAGL(4) + pidx, tv, __ATOMIC_RELAXED, __HIP_MEMORY_SCOPE_AGENT);
      // ---- D': slot4 -> s7(tanh) -> slot6 ----
      wait_tags(TAGL(4), tv, pb, tid);
      stage_panel_cw(S, 4, rt, smem, tid);
      __syncthreads();
      {
        float sv[4];
        gemm512<0, 0, false>(Wh, Wl, smem, 7, 7, cb, ln, l4, l15, sv, dum);
        store_state(sv, S, 6, rt, cb, fscrw, ln, l4, l15);
      }
      wait_vm(); __syncthreads();
      if (tid == 0)
        __hip_atomic_store(TAGL(6) + pidx, tv, __ATOMIC_RELAXED, __HIP_MEMORY_SCOPE_AGENT);
    }
  }
#undef TAGL
}

extern "C" void kernel_launch(void *const *d_in, const int *in_sizes, int n_in,
                              void *d_out, int out_size, void *d_ws, size_t ws_size,
                              hipStream_t stream) {
  const float *x = (const float *)d_in[0];
  const float *h0 = (const float *)d_in[1];
  const float *W0 = (const float *)d_in[2];
  const float *Ws = (const float *)d_in[3];
  float *out = (float *)d_out;
  u16 *ws = (u16 *)d_ws;

  hipMemsetAsync(d_ws, 0, 32768, stream);  // zero prologue counters + all tags

  void *args[] = {(void *)&x, (void *)&h0, (void *)&W0, (void *)&Ws, (void *)&out, (void *)&ws};
  hipError_t err = hipLaunchCooperativeKernel((void *)darts_rnn, dim3(256), dim3(256),
                                              args, 0, stream);
  if (err != hipSuccess) {
    (void)hipGetLastError();
    darts_rnn<<<dim3(256), dim3(256), 0, stream>>>(x, h0, W0, Ws, out, ws);
  }
}

// Round 14
// 15603.049 us; speedup vs baseline: 1.4986x; 1.2117x over previous
//
#include <hip/hip_runtime.h>

typedef __bf16 bf16x8 __attribute__((ext_vector_type(8)));
typedef float f32x4 __attribute__((ext_vector_type(4)));
typedef unsigned short u16;
typedef unsigned int u32;
typedef u16 u16x8 __attribute__((ext_vector_type(8)));

#define MFMA16(a, b, c) __builtin_amdgcn_mfma_f32_16x16x32_bf16((a), (b), (c), 0, 0, 0)

// ---------------------------------------------------------------------------
// R13 (18.9ms, P2P epoch tags) + single-plane intra-step states + reg-carried
// spv + early slot0-tag publish at E.
//
// Precision design: slot0 (h, the 256-step recursion) and ALL weights keep
// hi/lo bf16 pairs (3-term MFMA at A). Intra-step panels slot1..6 are single
// bf16 (2-term MFMA): panels are only GEMM A-operands (noise ~1e-4/step via
// W=±0.04); the activation s_prev path stays f32 in registers — each block's
// needed spv slice IS its own previous-round output slice (rows l4*4+j, cols
// cb*8+(l15>>1)). half0 chain: rs0->rs1->rs2->rs5 all reg-f32. half1's C'
// reads s1 from panel (bf16, enters mean /8 via s3/s7 only).
//
// Sync: P2P tags as R13. Producers: data stores -> wait_vm -> syncthreads ->
// tid0 tag (AGENT). Consumers poll one 64B tag line. WAR chain identical to
// R13 (panels same addresses, lo planes of slots 1-6 simply unused).
// E publishes slot0 tag BEFORE out-writes (out is off the dependency graph).
//
// counters (32768B memset 0): prologue gbar sub c*64 (c<8), top 512;
//   tags u32 at 1024 + (slot*8+rt)*16 + p.
// ws u16: Wh[5242880] @ byte 32768, Wl[5242880], S[7][131072]: slots
//   0=h(hi[8192]++lo[8192] per rt) 1=s0 2=s1 3=s2 4=s3 5=s5 6=s7 (hi only).
// All polls bounded; timeout collapses budget -> finish-wrong, never hang.
// ---------------------------------------------------------------------------

__device__ __forceinline__ u16 f2bf(float f) {
  u32 u = __float_as_uint(f);
  u += 0x7FFFu + ((u >> 16) & 1u);
  return (u16)(u >> 16);
}
__device__ __forceinline__ float bf2f(u32 h) { return __uint_as_float(h << 16); }
__device__ __forceinline__ void splitbf(float f, u16 &hi, u16 &lo) {
  hi = f2bf(f);
  lo = f2bf(f - bf2f((u32)hi));
}

__device__ __forceinline__ void issue_ld128_sc(bf16x8 &d, const u16 *p) {
  asm volatile("global_load_dwordx4 %0, %1, off sc0 sc1" : "=v"(d) : "v"(p));
}
__device__ __forceinline__ void issue_ld128u_sc(u16x8 &d, const u16 *p) {
  asm volatile("global_load_dwordx4 %0, %1, off sc0 sc1" : "=v"(d) : "v"(p));
}
__device__ __forceinline__ void st128_sc(u16 *p, u16x8 v) {
  asm volatile("global_store_dwordx4 %0, %1, off sc0 sc1" :: "v"(p), "v"(v) : "memory");
}
__device__ __forceinline__ void st16_sc(u16 *p, u16 v) {
  u32 q = v;
  asm volatile("global_store_short %0, %1, off sc0 sc1" :: "v"(p), "v"(q) : "memory");
}
__device__ __forceinline__ void wait_vm() {
  asm volatile("s_waitcnt vmcnt(0)" ::: "memory");
  __builtin_amdgcn_sched_barrier(0);
}
__device__ __forceinline__ void wait_vm_n(int n) {
  switch (n) {
    case 0: asm volatile("s_waitcnt vmcnt(0)" ::: "memory"); break;
    case 1: asm volatile("s_waitcnt vmcnt(1)" ::: "memory"); break;
    case 2: asm volatile("s_waitcnt vmcnt(2)" ::: "memory"); break;
    case 3: asm volatile("s_waitcnt vmcnt(3)" ::: "memory"); break;
    case 4: asm volatile("s_waitcnt vmcnt(4)" ::: "memory"); break;
    case 5: asm volatile("s_waitcnt vmcnt(5)" ::: "memory"); break;
    case 6: asm volatile("s_waitcnt vmcnt(6)" ::: "memory"); break;
    default: asm volatile("s_waitcnt vmcnt(7)" ::: "memory"); break;
  }
  __builtin_amdgcn_sched_barrier(0);
}

__device__ __forceinline__ int mbase(int m) {          // u16 elems; m=0 -> W0 (K=1024)
  return m == 0 ? 0 : 1048576 + (m - 1) * 524288;
}
__device__ __forceinline__ int lineOf(int row15, int scol) {
  return (scol >> 5) * 64 + row15 + ((scol >> 3) & 3) * 16;
}
__device__ __forceinline__ int goff(int slot, int row, int scol) {  // hi; (slot0 lo at +8192)
  return slot * 131072 + (row >> 4) * 16384 + lineOf(row & 15, scol) * 8 + (scol & 7);
}

template <int A> __device__ __forceinline__ float actf(float x) {
  if (A == 0) { float e = __expf(2.f * x); return 1.f - 2.f / (e + 1.f); } // tanh
  if (A == 1) return 1.f / (1.f + __expf(-x));                            // sigmoid
  if (A == 2) return fmaxf(x, 0.f);                                       // relu
  return x;                                                               // identity
}

__device__ __forceinline__ float lds_elem2(const u16 *lds, int row15, int scol) {  // hi+lo
  int o = lineOf(row15, scol) * 8 + (scol & 7);
  return bf2f(lds[o]) + bf2f(lds[o + 8192]);
}
__device__ __forceinline__ float lds_elem1(const u16 *lds, int row15, int scol) {  // hi only
  int o = lineOf(row15, scol) * 8 + (scol & 7);
  return bf2f(lds[o]);
}

// single-plane staged copy (16KB), counted ladder: enter with vmcnt==0 only
__device__ __forceinline__ void stage_sp_cw(const u16 *S, int slot, int rt, u16 *lds, int tid) {
  const u16 *src = S + slot * 131072 + rt * 16384 + tid * 8;
  bf16x8 r[4];
#pragma unroll
  for (int i = 0; i < 4; ++i) issue_ld128_sc(r[i], src + i * 2048);
#pragma unroll
  for (int i = 0; i < 4; ++i) {
    wait_vm_n(3 - i);
    *(bf16x8 *)(lds + tid * 8 + i * 2048) = r[i];
  }
}
// single-plane, full drain (safe with concurrent outstanding VMEM)
__device__ __forceinline__ void stage_sp_drain(const u16 *S, int slot, int rt, u16 *lds, int tid) {
  const u16 *src = S + slot * 131072 + rt * 16384 + tid * 8;
  bf16x8 r[4];
#pragma unroll
  for (int i = 0; i < 4; ++i) issue_ld128_sc(r[i], src + i * 2048);
  wait_vm();
#pragma unroll
  for (int i = 0; i < 4; ++i) *(bf16x8 *)(lds + tid * 8 + i * 2048) = r[i];
}
// dual-plane (32KB) staged copy for slot0, counted ladder
__device__ __forceinline__ void stage_dp_cw(const u16 *S, int slot, int rt, u16 *lds, int tid) {
  const u16 *src = S + slot * 131072 + rt * 16384 + tid * 8;
  bf16x8 r[8];
#pragma unroll
  for (int i = 0; i < 8; ++i) issue_ld128_sc(r[i], src + i * 2048);
#pragma unroll
  for (int i = 0; i < 8; ++i) {
    wait_vm_n(7 - i);
    *(bf16x8 *)(lds + tid * 8 + i * 2048) = r[i];
  }
}

template <int ACT>
__device__ __forceinline__ void act_only(f32x4 acc, const float *spv, float *sv) {
#pragma unroll
  for (int j = 0; j < 4; ++j) {
    float cp = acc[j];
    float hp = __shfl_xor(cp, 1);
    float sig = 1.f / (1.f + __expf(-cp));
    sv[j] = spv[j] + sig * (actf<ACT>(hp) - spv[j]);
  }
}

// single-plane state store: frag sv -> per-wave LDS transpose -> 1x16B/row
__device__ __forceinline__ void store_sp(const float *sv, u16 *S, int dslot,
                                         int rt, int cb, float *fscrw,
                                         int ln, int l4, int l15) {
  if ((l15 & 1) == 0) {
#pragma unroll
    for (int j = 0; j < 4; ++j) fscrw[(l4 * 4 + j) * 8 + (l15 >> 1)] = sv[j];
  }
  if (ln < 16) {
    u16x8 H;
#pragma unroll
    for (int c = 0; c < 8; ++c) H[c] = f2bf(fscrw[ln * 8 + c]);
    st128_sc(S + goff(dslot, rt * 16 + ln, cb * 8), H);
  }
}

// K=512 GEMM, single-plane A-panel from LDS, reg spv; 2 MFMA per weight pair
template <int ACT0, int ACT1, bool TWO>
__device__ __forceinline__ void gemm_sp(const u16 *Wh, const u16 *Wl, const u16 *lds,
                                        int m0, int m1, int cb, int ln, int l4, int l15,
                                        const float *spv, float *sv0, float *sv1) {
  f32x4 acc0 = {0.f, 0.f, 0.f, 0.f}, acc1 = {0.f, 0.f, 0.f, 0.f};
  const u16 *w0h = Wh + mbase(m0) + (cb * 16 * 64 + ln) * 8;
  const u16 *w0l = Wl + mbase(m0) + (cb * 16 * 64 + ln) * 8;
  const u16 *w1h = Wh + mbase(m1) + (cb * 16 * 64 + ln) * 8;
  const u16 *w1l = Wl + mbase(m1) + (cb * 16 * 64 + ln) * 8;
#pragma unroll
  for (int kc = 0; kc < 16; ++kc) {
    bf16x8 Ah = *(const bf16x8 *)(lds + (kc * 64 + ln) * 8);
    bf16x8 b0h = *(const bf16x8 *)(w0h + kc * 512);
    bf16x8 b0l = *(const bf16x8 *)(w0l + kc * 512);
    acc0 = MFMA16(Ah, b0h, acc0);
    acc0 = MFMA16(Ah, b0l, acc0);
    if (TWO) {
      bf16x8 b1h = *(const bf16x8 *)(w1h + kc * 512);
      bf16x8 b1l = *(const bf16x8 *)(w1l + kc * 512);
      acc1 = MFMA16(Ah, b1h, acc1);
      acc1 = MFMA16(Ah, b1l, acc1);
    }
  }
  act_only<ACT0>(acc0, spv, sv0);
  if (TWO) act_only<ACT1>(acc1, spv, sv1);
}

// round A: s0 = h + sigmoid(c)*(tanh(h') - h); A = [x_t | h], K=1024, W0.
// h panel hi/lo (3-term), x on-the-fly hi/lo split (3-term). Returns sv (f32).
__device__ __forceinline__ void roundA(const float *xin, int t, const u16 *Wh, const u16 *Wl,
                                       const u16 *lds, int rt, int cb, int ln, int l4, int l15,
                                       float *sv) {
  float spv[4];
#pragma unroll
  for (int j = 0; j < 4; ++j) spv[j] = lds_elem2(lds, l4 * 4 + j, cb * 8 + (l15 >> 1));
  f32x4 acc = {0.f, 0.f, 0.f, 0.f};
  const u16 *wh = Wh + (cb * 32 * 64 + ln) * 8;
  const u16 *wl = Wl + (cb * 32 * 64 + ln) * 8;
  const float *xp = xin + (t * 128 + rt * 16 + l15) * 512 + l4 * 8;
#pragma unroll
  for (int kc = 0; kc < 16; ++kc) {  // x half (k<512)
    f32x4 xa = *(const f32x4 *)(xp + kc * 32);
    f32x4 xb = *(const f32x4 *)(xp + kc * 32 + 4);
    union { u16 u[8]; bf16x8 v; } H, Lo;
#pragma unroll
    for (int e = 0; e < 4; ++e) {
      splitbf(xa[e], H.u[e], Lo.u[e]);
      splitbf(xb[e], H.u[4 + e], Lo.u[4 + e]);
    }
    bf16x8 bh = *(const bf16x8 *)(wh + kc * 512);
    bf16x8 bl = *(const bf16x8 *)(wl + kc * 512);
    acc = MFMA16(H.v, bh, acc);
    acc = MFMA16(H.v, bl, acc);
    acc = MFMA16(Lo.v, bh, acc);
  }
#pragma unroll
  for (int kc = 0; kc < 16; ++kc) {  // h half (k>=512), hi/lo from staged LDS
    bf16x8 Ah = *(const bf16x8 *)(lds + (kc * 64 + ln) * 8);
    bf16x8 Al = *(const bf16x8 *)(lds + 8192 + (kc * 64 + ln) * 8);
    bf16x8 bh = *(const bf16x8 *)(wh + (16 + kc) * 512);
    bf16x8 bl = *(const bf16x8 *)(wl + (16 + kc) * 512);
    acc = MFMA16(Ah, bh, acc);
    acc = MFMA16(Ah, bl, acc);
    acc = MFMA16(Al, bh, acc);
  }
  act_only<0>(acc, spv, sv);
}

// global hierarchical epoch barrier (prologue only), bounded polls
__device__ __forceinline__ void gbar(u32 *cnt, u32 &ep, u32 &pb) {
  wait_vm();
  __syncthreads();
  ep += 256u;
  if (threadIdx.x == 0) {
    const int c = blockIdx.x & 7;
    u32 old = __hip_atomic_fetch_add(&cnt[c * 64], 1u, __ATOMIC_RELAXED, __HIP_MEMORY_SCOPE_AGENT);
    if (((old + 1u) & 31u) == 0u)
      __hip_atomic_fetch_add(&cnt[512], 32u, __ATOMIC_RELAXED, __HIP_MEMORY_SCOPE_AGENT);
    bool ok = false;
    for (u32 i = 0; i < pb; ++i) {
      u32 v = __hip_atomic_load(&cnt[512], __ATOMIC_RELAXED, __HIP_MEMORY_SCOPE_AGENT);
      if ((int)(v - ep) >= 0) { ok = true; break; }
      __builtin_amdgcn_s_sleep(2);
    }
    if (!ok) pb = 4096u;
  }
  __syncthreads();
}

// wait until all 16 tags of one line are >= need (wave0 polls)
__device__ __forceinline__ void wait_tags(const u32 *line, u32 need, u32 &pb, int tid) {
  if (tid < 64) {
    const u32 *p = line + (tid & 15);
    const bool mine = tid < 16;
    bool ok = false;
    for (u32 i = 0; i < pb; ++i) {
      u32 v = mine ? __hip_atomic_load(p, __ATOMIC_RELAXED, __HIP_MEMORY_SCOPE_AGENT) : need;
      if (__all((int)(v - need) >= 0)) { ok = true; break; }
    }
    if (!ok) pb = 4096u;
  }
  __syncthreads();
}
// wait on three tag lines at once (lanes 0-15,16-31,32-47)
__device__ __forceinline__ void wait_tags3(const u32 *a, const u32 *b, const u32 *c,
                                           u32 need, u32 &pb, int tid) {
  if (tid < 64) {
    const u32 *p = (tid < 16) ? a + tid : (tid < 32) ? b + (tid - 16)
                  : (tid < 48) ? c + (tid - 32) : a;
    const bool mine = tid < 48;
    bool ok = false;
    for (u32 i = 0; i < pb; ++i) {
      u32 v = mine ? __hip_atomic_load(p, __ATOMIC_RELAXED, __HIP_MEMORY_SCOPE_AGENT) : need;
      if (__all((int)(v - need) >= 0)) { ok = true; break; }
    }
    if (!ok) pb = 4096u;
  }
  __syncthreads();
}

__global__ __launch_bounds__(256, 1) void darts_rnn(
    const float *__restrict__ xin, const float *__restrict__ h0in,
    const float *__restrict__ W0, const float *__restrict__ Wsi,
    float *__restrict__ out, u16 *__restrict__ wsu) {
  __shared__ u16 smem[16384];      // 32KB staging (A uses all; others 16KB)
  __shared__ float fscr[4][128];   // per-wave transpose scratch
  u32 *cnt = (u32 *)wsu;
  u16 *Wh = wsu + 16384;           // byte 32768
  u16 *Wl = Wh + 5242880;
  u16 *S = Wl + 5242880;

  const int tid = threadIdx.x, bid = blockIdx.x;
  const int ln = tid & 63, wid = tid >> 6;
  const int l15 = ln & 15, l4 = ln >> 4;
  const int rt = (bid & 127) >> 4;
  const int cb = (bid & 15) * 4 + wid;
  const int pidx = bid & 15;
  float *fscrw = fscr[wid];
#define TAGL(s) (cnt + 1024 + ((s) * 8 + rt) * 16)

  u32 ep = 0, pb = 1u << 21;

  // ---- hygiene: flush dirty ws lines (poison), then invalidate L2 ----
  if (wid == 0) asm volatile("buffer_wbl2 sc1" ::: "memory");
  wait_vm();
  gbar(cnt, ep, pb);
  if (wid == 0) asm volatile("buffer_inv sc1" ::: "memory");
  wait_vm();
  gbar(cnt, ep, pb);

  // ---- P0: weight hi/lo split into fragment layout ----
  for (int idx = bid * 256 + tid; idx < 5242880; idx += 65536) {
    int mk = idx >> 10, oc = idx & 1023;
    int m, k;
    if (mk < 1024) { m = 0; k = mk; } else { m = 1 + ((mk - 1024) >> 9); k = (mk - 1024) & 511; }
    float v = (m == 0) ? W0[k * 1024 + oc] : Wsi[((m - 1) * 512 + k) * 1024 + oc];
    int colp = (oc < 512) ? (oc * 2) : ((oc - 512) * 2 + 1);  // interleave c,h cols
    int cbw = colp >> 4;
    int kc = k >> 5;
    int lnn = (colp & 15) + ((k >> 3) & 3) * 16;
    int el = k & 7;
    int lineBase = (m == 0) ? (cbw * 32 + kc) : (cbw * 16 + kc);  // W0: K=1024
    int e = mbase(m) + (lineBase * 64 + lnn) * 8 + el;
    u16 hi, lo; splitbf(v, hi, lo);
    st16_sc(Wh + e, hi);
    st16_sc(Wl + e, lo);
  }
  {  // h0 -> slot 0 (hi/lo)
    int g = bid * 256 + tid;
    int row = g >> 9, k = g & 511;
    u16 hi, lo; splitbf(h0in[g], hi, lo);
    int o = goff(0, row, k);
    st16_sc(S + o, hi);
    st16_sc(S + o + 8192, lo);
  }
  gbar(cnt, ep, pb);   // weights + h0 + zeroed tags visible everywhere

  if (bid < 128) {
    // ================= half0 chain: A B C D E per step =================
    for (int t = 0; t < 256; ++t) {
      const u32 tv = (u32)(t + 1);
      float rs0[4], rs1[4], rs2[4], rs4[4], rs5[4], dum[4];
      // ---- A: slot0(hi/lo) -> s0 -> slot1(sp), rs0 ----
      wait_tags(TAGL(0), (u32)t, pb, tid);
      stage_dp_cw(S, 0, rt, smem, tid);
      __syncthreads();
      roundA(xin, t, Wh, Wl, smem, rt, cb, ln, l4, l15, rs0);
      store_sp(rs0, S, 1, rt, cb, fscrw, ln, l4, l15);
      wait_vm(); __syncthreads();
      if (tid == 0)
        __hip_atomic_store(TAGL(1) + pidx, tv, __ATOMIC_RELAXED, __HIP_MEMORY_SCOPE_AGENT);
      // ---- B: slot1 -> s1 (sig, spv=rs0) -> slot2, rs1 ----
      wait_tags(TAGL(1), tv, pb, tid);
      stage_sp_cw(S, 1, rt, smem, tid);
      __syncthreads();
      gemm_sp<1, 1, false>(Wh, Wl, smem, 1, 1, cb, ln, l4, l15, rs0, rs1, dum);
      store_sp(rs1, S, 2, rt, cb, fscrw, ln, l4, l15);
      wait_vm(); __syncthreads();
      if (tid == 0)
        __hip_atomic_store(TAGL(2) + pidx, tv, __ATOMIC_RELAXED, __HIP_MEMORY_SCOPE_AGENT);
      // ---- C: slot2 -> s2(relu)->slot3+rs2, s4(ident) reg-only (spv=rs1) ----
      wait_tags(TAGL(2), tv, pb, tid);
      stage_sp_cw(S, 2, rt, smem, tid);
      __syncthreads();
      gemm_sp<2, 3, true>(Wh, Wl, smem, 2, 4, cb, ln, l4, l15, rs1, rs2, rs4);
      store_sp(rs2, S, 3, rt, cb, fscrw, ln, l4, l15);
      wait_vm(); __syncthreads();
      if (tid == 0)
        __hip_atomic_store(TAGL(3) + pidx, tv, __ATOMIC_RELAXED, __HIP_MEMORY_SCOPE_AGENT);
      // ---- D: slot3 -> s5(tanh, spv=rs2) -> slot5 + rs5 ----
      wait_tags(TAGL(3), tv, pb, tid);
      stage_sp_cw(S, 3, rt, smem, tid);
      __syncthreads();
      gemm_sp<0, 0, false>(Wh, Wl, smem, 5, 5, cb, ln, l4, l15, rs2, rs5, dum);
      store_sp(rs5, S, 5, rt, cb, fscrw, ln, l4, l15);
      wait_vm(); __syncthreads();
      if (tid == 0)
        __hip_atomic_store(TAGL(5) + pidx, tv, __ATOMIC_RELAXED, __HIP_MEMORY_SCOPE_AGENT);
      // ---- E: slot5 -> s6(sig),s8(relu) (spv=rs5); mean -> slot0, tag, out ----
      wait_tags3(TAGL(5), TAGL(4), TAGL(6), tv, pb, tid);
      u16x8 p3h, p7h;
      if (ln < 16) {  // prefetch s3,s7 row-slices (single-plane)
        issue_ld128u_sc(p3h, S + goff(4, rt * 16 + ln, cb * 8));
        issue_ld128u_sc(p7h, S + goff(6, rt * 16 + ln, cb * 8));
      }
      stage_sp_drain(S, 5, rt, smem, tid);   // full drain covers prefetch
      __syncthreads();
      {
        float sv6[4], sv8[4];
        gemm_sp<1, 2, true>(Wh, Wl, smem, 6, 8, cb, ln, l4, l15, rs5, sv6, sv8);
        if ((l15 & 1) == 0) {
#pragma unroll
          for (int j = 0; j < 4; ++j)
            fscrw[(l4 * 4 + j) * 8 + (l15 >> 1)] =
                rs1[j] + rs2[j] + rs4[j] + rs5[j] + sv6[j] + sv8[j];
        }
        float o0[8];
        if (ln < 16) {
          u16x8 H, L;
#pragma unroll
          for (int c = 0; c < 8; ++c) {
            float v = fscrw[ln * 8 + c] + bf2f(p3h[c]) + bf2f(p7h[c]);
            float hnew = v * 0.125f;
            o0[c] = hnew;
            u16 hi, lo; splitbf(hnew, hi, lo);
            H[c] = hi; L[c] = lo;
          }
          u16 *p = S + goff(0, rt * 16 + ln, cb * 8);
          st128_sc(p, H);
          st128_sc(p + 8192, L);
        }
        wait_vm(); __syncthreads();        // slot0 drained everywhere
        if (tid == 0)                      // publish BEFORE out-writes
          __hip_atomic_store(TAGL(0) + pidx, tv, __ATOMIC_RELAXED, __HIP_MEMORY_SCOPE_AGENT);
        if (ln < 16) {                     // out-writes off the critical hop
          int row = rt * 16 + ln;
          float *op = out + t * 65536 + row * 512 + cb * 8;
          *(f32x4 *)op = *(f32x4 *)&o0[0];
          *(f32x4 *)(op + 4) = *(f32x4 *)&o0[4];
          if (t == 255) {
            float *op2 = out + 16777216 + row * 512 + cb * 8;
            *(f32x4 *)op2 = *(f32x4 *)&o0[0];
            *(f32x4 *)(op2 + 4) = *(f32x4 *)&o0[4];
          }
        }
        wait_vm();                         // vmcnt==0 before next stage ladder
      }
    }
  } else {
    // ================= half1 chain: C' D' per step =================
    for (int t = 0; t < 256; ++t) {
      const u32 tv = (u32)(t + 1);
      float sv3[4], dum[4];
      // ---- C': slot2 -> s3(relu, spv=s1 from panel) -> slot4 ----
      wait_tags(TAGL(2), tv, pb, tid);
      stage_sp_cw(S, 2, rt, smem, tid);
      __syncthreads();
      {
        float spv[4];
#pragma unroll
        for (int j = 0; j < 4; ++j) spv[j] = lds_elem1(smem, l4 * 4 + j, cb * 8 + (l15 >> 1));
        gemm_sp<2, 2, false>(Wh, Wl, smem, 3, 3, cb, ln, l4, l15, spv, sv3, dum);
        store_sp(sv3, S, 4, rt, cb, fscrw, ln, l4, l15);
      }
      wait_vm(); __syncthreads();
      if (tid == 0)
        __hip_atomic_store(TAGL(4) + pidx, tv, __ATOMIC_RELAXED, __HIP_MEMORY_SCOPE_AGENT);
      // ---- D': slot4 -> s7(tanh, spv=sv3 reg) -> slot6 ----
      wait_tags(TAGL(4), tv, pb, tid);
      stage_sp_cw(S, 4, rt, smem, tid);
      __syncthreads();
      {
        float sv[4];
        gemm_sp<0, 0, false>(Wh, Wl, smem, 7, 7, cb, ln, l4, l15, sv3, sv, dum);
        store_sp(sv, S, 6, rt, cb, fscrw, ln, l4, l15);
      }
      wait_vm(); __syncthreads();
      if (tid == 0)
        __hip_atomic_store(TAGL(6) + pidx, tv, __ATOMIC_RELAXED, __HIP_MEMORY_SCOPE_AGENT);
    }
  }
#undef TAGL
}

extern "C" void kernel_launch(void *const *d_in, const int *in_sizes, int n_in,
                              void *d_out, int out_size, void *d_ws, size_t ws_size,
                              hipStream_t stream) {
  const float *x = (const float *)d_in[0];
  const float *h0 = (const float *)d_in[1];
  const float *W0 = (const float *)d_in[2];
  const float *Ws = (const float *)d_in[3];
  float *out = (float *)d_out;
  u16 *ws = (u16 *)d_ws;

  hipMemsetAsync(d_ws, 0, 32768, stream);  // zero prologue counters + all tags

  void *args[] = {(void *)&x, (void *)&h0, (void *)&W0, (void *)&Ws, (void *)&out, (void *)&ws};
  hipError_t err = hipLaunchCooperativeKernel((void *)darts_rnn, dim3(256), dim3(256),
                                              args, 0, stream);
  if (err != hipSuccess) {
    (void)hipGetLastError();
    darts_rnn<<<dim3(256), dim3(256), 0, stream>>>(x, h0, W0, Ws, out, ws);
  }
}

// Round 15
// 11805.817 us; speedup vs baseline: 1.9806x; 1.3216x over previous
//
#include <hip/hip_runtime.h>

typedef __bf16 bf16x8 __attribute__((ext_vector_type(8)));
typedef float f32x4 __attribute__((ext_vector_type(4)));
typedef unsigned short u16;
typedef unsigned int u32;
typedef u16 u16x8 __attribute__((ext_vector_type(8)));

#define MFMA16(a, b, c) __builtin_amdgcn_mfma_f32_16x16x32_bf16((a), (b), (c), 0, 0, 0)

// ---------------------------------------------------------------------------
// R14 (15.6ms) + three latency cuts:
//  1) xpre offload: half1 computes x_{t+1}@W0[:512] (3-term, raw f32 preact)
//     during step t, stored in the consumer's acc fragment layout (16B/lane).
//     A = stage(slot0) + h-GEMM + xpre-add. WAR safe via slot2->slot4->D'.
//  2) per-wave incremental staging: wave w gates on producer tags
//     {w,w+4,w+8,w+12} then ladder-loads those 1KB slices (slice p = u16
//     [p*512,(p+1)*512) of the rt panel). Absorbs producer skew.
//  3) E defers slot4/slot6: poll only partner tag AFTER the GEMM, then load
//     2x16B (cols cb*8..+7 live in producer pidx's slice; single line).
//
// Precision: slot0 + weights hi/lo (3-term); slots1..6 single bf16 (2-term);
// spv reg-carried f32 (rs0->rs1->rs2->rs5). Same as R14.
// Sync: P2P tags (AGENT/LLC, memset-zeroed). All polls bounded.
//
// counters (32768B memset 0): gbar sub c*64 (c<8), top 512;
//   state tags u32 @ 1024+(slot*8+rt)*16+p (slot 0..6); xpre tags slot idx 7.
// ws u16: Wh[5242880] @ byte 32768, Wl[5242880], S[7][131072]
//   (slot0 hi+lo planes; slots1-6 hi only), XS[262144] (xpre f32, 16B/lane).
// ---------------------------------------------------------------------------

__device__ __forceinline__ u16 f2bf(float f) {
  u32 u = __float_as_uint(f);
  u += 0x7FFFu + ((u >> 16) & 1u);
  return (u16)(u >> 16);
}
__device__ __forceinline__ float bf2f(u32 h) { return __uint_as_float(h << 16); }
__device__ __forceinline__ void splitbf(float f, u16 &hi, u16 &lo) {
  hi = f2bf(f);
  lo = f2bf(f - bf2f((u32)hi));
}

__device__ __forceinline__ void issue_ld128_sc(bf16x8 &d, const u16 *p) {
  asm volatile("global_load_dwordx4 %0, %1, off sc0 sc1" : "=v"(d) : "v"(p));
}
__device__ __forceinline__ void issue_ld128u_sc(u16x8 &d, const u16 *p) {
  asm volatile("global_load_dwordx4 %0, %1, off sc0 sc1" : "=v"(d) : "v"(p));
}
__device__ __forceinline__ void st128_sc(u16 *p, u16x8 v) {
  asm volatile("global_store_dwordx4 %0, %1, off sc0 sc1" :: "v"(p), "v"(v) : "memory");
}
__device__ __forceinline__ void st16_sc(u16 *p, u16 v) {
  u32 q = v;
  asm volatile("global_store_short %0, %1, off sc0 sc1" :: "v"(p), "v"(q) : "memory");
}
__device__ __forceinline__ void wait_vm() {
  asm volatile("s_waitcnt vmcnt(0)" ::: "memory");
  __builtin_amdgcn_sched_barrier(0);
}
__device__ __forceinline__ void wait_vm_n(int n) {
  switch (n) {
    case 0: asm volatile("s_waitcnt vmcnt(0)" ::: "memory"); break;
    case 1: asm volatile("s_waitcnt vmcnt(1)" ::: "memory"); break;
    case 2: asm volatile("s_waitcnt vmcnt(2)" ::: "memory"); break;
    case 3: asm volatile("s_waitcnt vmcnt(3)" ::: "memory"); break;
    case 4: asm volatile("s_waitcnt vmcnt(4)" ::: "memory"); break;
    case 5: asm volatile("s_waitcnt vmcnt(5)" ::: "memory"); break;
    case 6: asm volatile("s_waitcnt vmcnt(6)" ::: "memory"); break;
    default: asm volatile("s_waitcnt vmcnt(7)" ::: "memory"); break;
  }
  __builtin_amdgcn_sched_barrier(0);
}

__device__ __forceinline__ int mbase(int m) {          // u16 elems; m=0 -> W0 (K=1024)
  return m == 0 ? 0 : 1048576 + (m - 1) * 524288;
}
__device__ __forceinline__ int lineOf(int row15, int scol) {
  return (scol >> 5) * 64 + row15 + ((scol >> 3) & 3) * 16;
}
__device__ __forceinline__ int goff(int slot, int row, int scol) {  // hi; (slot0 lo +8192)
  return slot * 131072 + (row >> 4) * 16384 + lineOf(row & 15, scol) * 8 + (scol & 7);
}

template <int A> __device__ __forceinline__ float actf(float x) {
  if (A == 0) { float e = __expf(2.f * x); return 1.f - 2.f / (e + 1.f); } // tanh
  if (A == 1) return 1.f / (1.f + __expf(-x));                            // sigmoid
  if (A == 2) return fmaxf(x, 0.f);                                       // relu
  return x;                                                               // identity
}

__device__ __forceinline__ float lds_elem2(const u16 *lds, int row15, int scol) {  // hi+lo
  int o = lineOf(row15, scol) * 8 + (scol & 7);
  return bf2f(lds[o]) + bf2f(lds[o + 8192]);
}
__device__ __forceinline__ float lds_elem1(const u16 *lds, int row15, int scol) {  // hi
  int o = lineOf(row15, scol) * 8 + (scol & 7);
  return bf2f(lds[o]);
}

// per-wave incremental single-plane stage: gate 4 producer tags, 4-ld ladder.
// Enter with vmcnt==0 for this wave (gate's atomic_load use forces drain).
__device__ __forceinline__ void stage_sp_inc(const u16 *S, int slot, int rt, u16 *lds,
                                             const u32 *tagl, u32 need, u32 &pb,
                                             int wid, int ln) {
  {
    const u32 *tp = tagl + wid + (ln & 3) * 4;
    bool ok = false;
    for (u32 i = 0; i < pb; ++i) {
      u32 v = __hip_atomic_load(tp, __ATOMIC_RELAXED, __HIP_MEMORY_SCOPE_AGENT);
      if (__all((int)(v - need) >= 0)) { ok = true; break; }
    }
    if (!ok) pb = 4096u;
  }
  const u16 *base = S + slot * 131072 + rt * 16384;
  bf16x8 r[4];
#pragma unroll
  for (int q = 0; q < 4; ++q)
    issue_ld128_sc(r[q], base + (wid + q * 4) * 512 + ln * 8);
#pragma unroll
  for (int q = 0; q < 4; ++q) {
    wait_vm_n(3 - q);
    *(bf16x8 *)(lds + (wid + q * 4) * 512 + ln * 8) = r[q];
  }
}
// dual-plane (slot0) variant: 8-ld ladder
__device__ __forceinline__ void stage_dp_inc(const u16 *S, int slot, int rt, u16 *lds,
                                             const u32 *tagl, u32 need, u32 &pb,
                                             int wid, int ln) {
  {
    const u32 *tp = tagl + wid + (ln & 3) * 4;
    bool ok = false;
    for (u32 i = 0; i < pb; ++i) {
      u32 v = __hip_atomic_load(tp, __ATOMIC_RELAXED, __HIP_MEMORY_SCOPE_AGENT);
      if (__all((int)(v - need) >= 0)) { ok = true; break; }
    }
    if (!ok) pb = 4096u;
  }
  const u16 *base = S + slot * 131072 + rt * 16384;
  bf16x8 r[8];
#pragma unroll
  for (int q = 0; q < 4; ++q) {
    issue_ld128_sc(r[q * 2], base + (wid + q * 4) * 512 + ln * 8);
    issue_ld128_sc(r[q * 2 + 1], base + 8192 + (wid + q * 4) * 512 + ln * 8);
  }
#pragma unroll
  for (int i = 0; i < 8; ++i) {
    wait_vm_n(7 - i);
    int q = i >> 1;
    *(bf16x8 *)(lds + ((i & 1) ? 8192 : 0) + (wid + q * 4) * 512 + ln * 8) = r[i];
  }
}

template <int ACT>
__device__ __forceinline__ void act_only(f32x4 acc, const float *spv, float *sv) {
#pragma unroll
  for (int j = 0; j < 4; ++j) {
    float cp = acc[j];
    float hp = __shfl_xor(cp, 1);
    float sig = 1.f / (1.f + __expf(-cp));
    sv[j] = spv[j] + sig * (actf<ACT>(hp) - spv[j]);
  }
}

// single-plane state store via per-wave LDS transpose -> 1x16B/row
__device__ __forceinline__ void store_sp(const float *sv, u16 *S, int dslot,
                                         int rt, int cb, float *fscrw,
                                         int ln, int l4, int l15) {
  if ((l15 & 1) == 0) {
#pragma unroll
    for (int j = 0; j < 4; ++j) fscrw[(l4 * 4 + j) * 8 + (l15 >> 1)] = sv[j];
  }
  if (ln < 16) {
    u16x8 H;
#pragma unroll
    for (int c = 0; c < 8; ++c) H[c] = f2bf(fscrw[ln * 8 + c]);
    st128_sc(S + goff(dslot, rt * 16 + ln, cb * 8), H);
  }
}

// K=512 GEMM, single-plane A from LDS, reg spv; 2 MFMA per weight pair
template <int ACT0, int ACT1, bool TWO>
__device__ __forceinline__ void gemm_sp(const u16 *Wh, const u16 *Wl, const u16 *lds,
                                        int m0, int m1, int cb, int ln, int l4, int l15,
                                        const float *spv, float *sv0, float *sv1) {
  f32x4 acc0 = {0.f, 0.f, 0.f, 0.f}, acc1 = {0.f, 0.f, 0.f, 0.f};
  const u16 *w0h = Wh + mbase(m0) + (cb * 16 * 64 + ln) * 8;
  const u16 *w0l = Wl + mbase(m0) + (cb * 16 * 64 + ln) * 8;
  const u16 *w1h = Wh + mbase(m1) + (cb * 16 * 64 + ln) * 8;
  const u16 *w1l = Wl + mbase(m1) + (cb * 16 * 64 + ln) * 8;
#pragma unroll
  for (int kc = 0; kc < 16; ++kc) {
    bf16x8 Ah = *(const bf16x8 *)(lds + (kc * 64 + ln) * 8);
    bf16x8 b0h = *(const bf16x8 *)(w0h + kc * 512);
    bf16x8 b0l = *(const bf16x8 *)(w0l + kc * 512);
    acc0 = MFMA16(Ah, b0h, acc0);
    acc0 = MFMA16(Ah, b0l, acc0);
    if (TWO) {
      bf16x8 b1h = *(const bf16x8 *)(w1h + kc * 512);
      bf16x8 b1l = *(const bf16x8 *)(w1l + kc * 512);
      acc1 = MFMA16(Ah, b1h, acc1);
      acc1 = MFMA16(Ah, b1l, acc1);
    }
  }
  act_only<ACT0>(acc0, spv, sv0);
  if (TWO) act_only<ACT1>(acc1, spv, sv1);
}

// A's h-phase GEMM (K=512..1023 of W0), dual-plane A-panel, 3-term
__device__ __forceinline__ f32x4 gemmA_h(const u16 *Wh, const u16 *Wl, const u16 *lds,
                                         int cb, int ln) {
  f32x4 acc = {0.f, 0.f, 0.f, 0.f};
  const u16 *wh = Wh + (cb * 32 * 64 + ln) * 8;
  const u16 *wl = Wl + (cb * 32 * 64 + ln) * 8;
#pragma unroll
  for (int kc = 0; kc < 16; ++kc) {
    bf16x8 Ah = *(const bf16x8 *)(lds + (kc * 64 + ln) * 8);
    bf16x8 Al = *(const bf16x8 *)(lds + 8192 + (kc * 64 + ln) * 8);
    bf16x8 bh = *(const bf16x8 *)(wh + (16 + kc) * 512);
    bf16x8 bl = *(const bf16x8 *)(wl + (16 + kc) * 512);
    acc = MFMA16(Ah, bh, acc);
    acc = MFMA16(Ah, bl, acc);
    acc = MFMA16(Al, bh, acc);
  }
  return acc;
}

// xpre producer: x_s @ W0[:512] (3-term), raw f32 preact -> XS (16B/lane)
__device__ __forceinline__ void xgemm_store(const float *xin, int s, int rt,
                                            const u16 *Wh, const u16 *Wl, u16 *XS,
                                            int cb, int ln, int l4, int l15) {
  f32x4 acc = {0.f, 0.f, 0.f, 0.f};
  const u16 *wh = Wh + (cb * 32 * 64 + ln) * 8;
  const u16 *wl = Wl + (cb * 32 * 64 + ln) * 8;
  const float *xp = xin + (s * 128 + rt * 16 + l15) * 512 + l4 * 8;
#pragma unroll
  for (int kc = 0; kc < 16; ++kc) {
    f32x4 xa = *(const f32x4 *)(xp + kc * 32);
    f32x4 xb = *(const f32x4 *)(xp + kc * 32 + 4);
    union { u16 u[8]; bf16x8 v; } H, Lo;
#pragma unroll
    for (int e = 0; e < 4; ++e) {
      splitbf(xa[e], H.u[e], Lo.u[e]);
      splitbf(xb[e], H.u[4 + e], Lo.u[4 + e]);
    }
    bf16x8 bh = *(const bf16x8 *)(wh + kc * 512);
    bf16x8 bl = *(const bf16x8 *)(wl + kc * 512);
    acc = MFMA16(H.v, bh, acc);
    acc = MFMA16(H.v, bl, acc);
    acc = MFMA16(Lo.v, bh, acc);
  }
  union { f32x4 f; u16x8 u; } cv;
  cv.f = acc;
  st128_sc(XS + (size_t)((rt * 64 + cb) * 64 + ln) * 8, cv.u);
}

// global hierarchical epoch barrier (prologue only), bounded polls
__device__ __forceinline__ void gbar(u32 *cnt, u32 &ep, u32 &pb) {
  wait_vm();
  __syncthreads();
  ep += 256u;
  if (threadIdx.x == 0) {
    const int c = blockIdx.x & 7;
    u32 old = __hip_atomic_fetch_add(&cnt[c * 64], 1u, __ATOMIC_RELAXED, __HIP_MEMORY_SCOPE_AGENT);
    if (((old + 1u) & 31u) == 0u)
      __hip_atomic_fetch_add(&cnt[512], 32u, __ATOMIC_RELAXED, __HIP_MEMORY_SCOPE_AGENT);
    bool ok = false;
    for (u32 i = 0; i < pb; ++i) {
      u32 v = __hip_atomic_load(&cnt[512], __ATOMIC_RELAXED, __HIP_MEMORY_SCOPE_AGENT);
      if ((int)(v - ep) >= 0) { ok = true; break; }
      __builtin_amdgcn_s_sleep(2);
    }
    if (!ok) pb = 4096u;
  }
  __syncthreads();
}

__global__ __launch_bounds__(256, 1) void darts_rnn(
    const float *__restrict__ xin, const float *__restrict__ h0in,
    const float *__restrict__ W0, const float *__restrict__ Wsi,
    float *__restrict__ out, u16 *__restrict__ wsu) {
  __shared__ u16 smem[16384];      // 32KB staging (A dual-plane; others 16KB)
  __shared__ float fscr[4][128];   // per-wave transpose scratch
  u32 *cnt = (u32 *)wsu;
  u16 *Wh = wsu + 16384;           // byte 32768
  u16 *Wl = Wh + 5242880;
  u16 *S = Wl + 5242880;
  u16 *XS = S + 7 * 131072;        // xpre region (512KB)

  const int tid = threadIdx.x, bid = blockIdx.x;
  const int ln = tid & 63, wid = tid >> 6;
  const int l15 = ln & 15, l4 = ln >> 4;
  const int rt = (bid & 127) >> 4;
  const int cb = (bid & 15) * 4 + wid;
  const int pidx = bid & 15;
  float *fscrw = fscr[wid];
#define TAGL(s) (cnt + 1024 + ((s) * 8 + rt) * 16)
#define XTAG (cnt + 1024 + (7 * 8 + rt) * 16)

  u32 ep = 0, pb = 1u << 21;

  // ---- hygiene: flush dirty ws lines (poison), then invalidate L2 ----
  if (wid == 0) asm volatile("buffer_wbl2 sc1" ::: "memory");
  wait_vm();
  gbar(cnt, ep, pb);
  if (wid == 0) asm volatile("buffer_inv sc1" ::: "memory");
  wait_vm();
  gbar(cnt, ep, pb);

  // ---- P0: weight hi/lo split into fragment layout ----
  for (int idx = bid * 256 + tid; idx < 5242880; idx += 65536) {
    int mk = idx >> 10, oc = idx & 1023;
    int m, k;
    if (mk < 1024) { m = 0; k = mk; } else { m = 1 + ((mk - 1024) >> 9); k = (mk - 1024) & 511; }
    float v = (m == 0) ? W0[k * 1024 + oc] : Wsi[((m - 1) * 512 + k) * 1024 + oc];
    int colp = (oc < 512) ? (oc * 2) : ((oc - 512) * 2 + 1);  // interleave c,h cols
    int cbw = colp >> 4;
    int kc = k >> 5;
    int lnn = (colp & 15) + ((k >> 3) & 3) * 16;
    int el = k & 7;
    int lineBase = (m == 0) ? (cbw * 32 + kc) : (cbw * 16 + kc);  // W0: K=1024
    int e = mbase(m) + (lineBase * 64 + lnn) * 8 + el;
    u16 hi, lo; splitbf(v, hi, lo);
    st16_sc(Wh + e, hi);
    st16_sc(Wl + e, lo);
  }
  {  // h0 -> slot 0 (hi/lo)
    int g = bid * 256 + tid;
    int row = g >> 9, k = g & 511;
    u16 hi, lo; splitbf(h0in[g], hi, lo);
    int o = goff(0, row, k);
    st16_sc(S + o, hi);
    st16_sc(S + o + 8192, lo);
  }
  gbar(cnt, ep, pb);   // weights + h0 + zeroed tags visible everywhere

  if (bid < 128) {
    // ================= half0 chain: A B C D E per step =================
    for (int t = 0; t < 256; ++t) {
      const u32 tv = (u32)(t + 1);
      float rs0[4], rs1[4], rs2[4], rs4[4], rs5[4], dum[4];
      // ---- A: slot0(hi/lo) + xpre -> s0 -> slot1 ----
      stage_dp_inc(S, 0, rt, smem, TAGL(0), (u32)t, pb, wid, ln);
      __syncthreads();
      {
        f32x4 acc = gemmA_h(Wh, Wl, smem, cb, ln);
        float spv0[4];
#pragma unroll
        for (int j = 0; j < 4; ++j) spv0[j] = lds_elem2(smem, l4 * 4 + j, cb * 8 + (l15 >> 1));
        {  // partner xpre (published after D'[t-1]; ~zero wait)
          const u32 *xt = XTAG + pidx;
          bool ok = false;
          for (u32 i = 0; i < pb; ++i) {
            u32 v = __hip_atomic_load(xt, __ATOMIC_RELAXED, __HIP_MEMORY_SCOPE_AGENT);
            if ((int)(v - tv) >= 0) { ok = true; break; }
          }
          if (!ok) pb = 4096u;
        }
        union { u16x8 u; f32x4 f; } xv;
        issue_ld128u_sc(xv.u, XS + (size_t)((rt * 64 + cb) * 64 + ln) * 8);
        wait_vm();
        acc = acc + xv.f;
        act_only<0>(acc, spv0, rs0);
      }
      store_sp(rs0, S, 1, rt, cb, fscrw, ln, l4, l15);
      wait_vm(); __syncthreads();
      if (tid == 0)
        __hip_atomic_store(TAGL(1) + pidx, tv, __ATOMIC_RELAXED, __HIP_MEMORY_SCOPE_AGENT);
      // ---- B: slot1 -> s1 (sig, spv=rs0) -> slot2 ----
      stage_sp_inc(S, 1, rt, smem, TAGL(1), tv, pb, wid, ln);
      __syncthreads();
      gemm_sp<1, 1, false>(Wh, Wl, smem, 1, 1, cb, ln, l4, l15, rs0, rs1, dum);
      store_sp(rs1, S, 2, rt, cb, fscrw, ln, l4, l15);
      wait_vm(); __syncthreads();
      if (tid == 0)
        __hip_atomic_store(TAGL(2) + pidx, tv, __ATOMIC_RELAXED, __HIP_MEMORY_SCOPE_AGENT);
      // ---- C: slot2 -> s2(relu)->slot3+rs2, s4(ident) reg (spv=rs1) ----
      stage_sp_inc(S, 2, rt, smem, TAGL(2), tv, pb, wid, ln);
      __syncthreads();
      gemm_sp<2, 3, true>(Wh, Wl, smem, 2, 4, cb, ln, l4, l15, rs1, rs2, rs4);
      store_sp(rs2, S, 3, rt, cb, fscrw, ln, l4, l15);
      wait_vm(); __syncthreads();
      if (tid == 0)
        __hip_atomic_store(TAGL(3) + pidx, tv, __ATOMIC_RELAXED, __HIP_MEMORY_SCOPE_AGENT);
      // ---- D: slot3 -> s5(tanh, spv=rs2) -> slot5 + rs5 ----
      stage_sp_inc(S, 3, rt, smem, TAGL(3), tv, pb, wid, ln);
      __syncthreads();
      gemm_sp<0, 0, false>(Wh, Wl, smem, 5, 5, cb, ln, l4, l15, rs2, rs5, dum);
      store_sp(rs5, S, 5, rt, cb, fscrw, ln, l4, l15);
      wait_vm(); __syncthreads();
      if (tid == 0)
        __hip_atomic_store(TAGL(5) + pidx, tv, __ATOMIC_RELAXED, __HIP_MEMORY_SCOPE_AGENT);
      // ---- E: slot5 -> s6(sig),s8(relu) (spv=rs5); partner s3,s7; mean ----
      stage_sp_inc(S, 5, rt, smem, TAGL(5), tv, pb, wid, ln);
      __syncthreads();
      {
        float sv6[4], sv8[4];
        gemm_sp<1, 2, true>(Wh, Wl, smem, 6, 8, cb, ln, l4, l15, rs5, sv6, sv8);
        {  // deferred partner-slice wait (s3 at C'[t], s7 at D'[t]; ~zero wait)
          const u32 *t4p = TAGL(4) + pidx, *t6p = TAGL(6) + pidx;
          bool ok = false;
          for (u32 i = 0; i < pb; ++i) {
            u32 v4 = __hip_atomic_load(t4p, __ATOMIC_RELAXED, __HIP_MEMORY_SCOPE_AGENT);
            u32 v6 = __hip_atomic_load(t6p, __ATOMIC_RELAXED, __HIP_MEMORY_SCOPE_AGENT);
            if ((int)(v4 - tv) >= 0 && (int)(v6 - tv) >= 0) { ok = true; break; }
          }
          if (!ok) pb = 4096u;
        }
        u16x8 p3h, p7h;
        if (ln < 16) {
          issue_ld128u_sc(p3h, S + goff(4, rt * 16 + ln, cb * 8));
          issue_ld128u_sc(p7h, S + goff(6, rt * 16 + ln, cb * 8));
        }
        wait_vm();
        if ((l15 & 1) == 0) {
#pragma unroll
          for (int j = 0; j < 4; ++j)
            fscrw[(l4 * 4 + j) * 8 + (l15 >> 1)] =
                rs1[j] + rs2[j] + rs4[j] + rs5[j] + sv6[j] + sv8[j];
        }
        float o0[8];
        if (ln < 16) {
          u16x8 H, L;
#pragma unroll
          for (int c = 0; c < 8; ++c) {
            float v = fscrw[ln * 8 + c] + bf2f(p3h[c]) + bf2f(p7h[c]);
            float hnew = v * 0.125f;
            o0[c] = hnew;
            u16 hi, lo; splitbf(hnew, hi, lo);
            H[c] = hi; L[c] = lo;
          }
          u16 *p = S + goff(0, rt * 16 + ln, cb * 8);
          st128_sc(p, H);
          st128_sc(p + 8192, L);
        }
        wait_vm(); __syncthreads();        // slot0 drained everywhere
        if (tid == 0)                      // publish BEFORE out-writes
          __hip_atomic_store(TAGL(0) + pidx, tv, __ATOMIC_RELAXED, __HIP_MEMORY_SCOPE_AGENT);
        if (ln < 16) {                     // out-writes off the critical hop
          int row = rt * 16 + ln;
          float *op = out + t * 65536 + row * 512 + cb * 8;
          *(f32x4 *)op = *(f32x4 *)&o0[0];
          *(f32x4 *)(op + 4) = *(f32x4 *)&o0[4];
          if (t == 255) {
            float *op2 = out + 16777216 + row * 512 + cb * 8;
            *(f32x4 *)op2 = *(f32x4 *)&o0[0];
            *(f32x4 *)(op2 + 4) = *(f32x4 *)&o0[4];
          }
        }
        wait_vm();                         // vmcnt==0 before next gate/ladder
      }
    }
  } else {
    // ================= half1 chain: C' D' + xpre per step =================
    // prologue: xpre for step 0
    xgemm_store(xin, 0, rt, Wh, Wl, XS, cb, ln, l4, l15);
    wait_vm(); __syncthreads();
    if (tid == 0)
      __hip_atomic_store(XTAG + pidx, 1u, __ATOMIC_RELAXED, __HIP_MEMORY_SCOPE_AGENT);
    for (int t = 0; t < 256; ++t) {
      const u32 tv = (u32)(t + 1);
      float sv3[4], dum[4];
      // ---- C': slot2 -> s3(relu, spv=s1 panel) -> slot4 ----
      stage_sp_inc(S, 2, rt, smem, TAGL(2), tv, pb, wid, ln);
      __syncthreads();
      {
        float spv[4];
#pragma unroll
        for (int j = 0; j < 4; ++j) spv[j] = lds_elem1(smem, l4 * 4 + j, cb * 8 + (l15 >> 1));
        gemm_sp<2, 2, false>(Wh, Wl, smem, 3, 3, cb, ln, l4, l15, spv, sv3, dum);
        store_sp(sv3, S, 4, rt, cb, fscrw, ln, l4, l15);
      }
      wait_vm(); __syncthreads();
      if (tid == 0)
        __hip_atomic_store(TAGL(4) + pidx, tv, __ATOMIC_RELAXED, __HIP_MEMORY_SCOPE_AGENT);
      // ---- D': slot4 -> s7(tanh, spv=sv3 reg) -> slot6 ----
      stage_sp_inc(S, 4, rt, smem, TAGL(4), tv, pb, wid, ln);
      __syncthreads();
      {
        float sv[4];
        gemm_sp<0, 0, false>(Wh, Wl, smem, 7, 7, cb, ln, l4, l15, sv3, sv, dum);
        store_sp(sv, S, 6, rt, cb, fscrw, ln, l4, l15);
      }
      wait_vm(); __syncthreads();
      if (tid == 0)
        __hip_atomic_store(TAGL(6) + pidx, tv, __ATOMIC_RELAXED, __HIP_MEMORY_SCOPE_AGENT);
      // ---- xpre for step t+1 (WAR safe: partner consumed xpre[t] before B[t],
      //      and D'[t] is ordered after slot2[t] -> slot4[t]) ----
      if (t < 255) {
        xgemm_store(xin, t + 1, rt, Wh, Wl, XS, cb, ln, l4, l15);
        wait_vm(); __syncthreads();
        if (tid == 0)
          __hip_atomic_store(XTAG + pidx, (u32)(t + 2), __ATOMIC_RELAXED, __HIP_MEMORY_SCOPE_AGENT);
      }
    }
  }
#undef TAGL
#undef XTAG
}

extern "C" void kernel_launch(void *const *d_in, const int *in_sizes, int n_in,
                              void *d_out, int out_size, void *d_ws, size_t ws_size,
                              hipStream_t stream) {
  const float *x = (const float *)d_in[0];
  const float *h0 = (const float *)d_in[1];
  const float *W0 = (const float *)d_in[2];
  const float *Ws = (const float *)d_in[3];
  float *out = (float *)d_out;
  u16 *ws = (u16 *)d_ws;

  hipMemsetAsync(d_ws, 0, 32768, stream);  // zero prologue counters + all tags

  void *args[] = {(void *)&x, (void *)&h0, (void *)&W0, (void *)&Ws, (void *)&out, (void *)&ws};
  hipError_t err = hipLaunchCooperativeKernel((void *)darts_rnn, dim3(256), dim3(256),
                                              args, 0, stream);
  if (err != hipSuccess) {
    (void)hipGetLastError();
    darts_rnn<<<dim3(256), dim3(256), 0, stream>>>(x, h0, W0, Ws, out, ws);
  }
}